// Round 1
// baseline (418.862 us; speedup 1.0000x reference)
//
#include <hip/hip_runtime.h>
#include <stdint.h>

#define AS1 __attribute__((address_space(1)))
#define AS3 __attribute__((address_space(3)))

typedef short v8s __attribute__((ext_vector_type(8)));
typedef float v4f __attribute__((ext_vector_type(4)));

__device__ __forceinline__ float b2f(unsigned short u) {
  return __uint_as_float(((unsigned int)u) << 16);
}
__device__ __forceinline__ unsigned short f2bu(float f) {
  unsigned int u = __float_as_uint(f);
  u += 0x7fffu + ((u >> 16) & 1u);
  return (unsigned short)(u >> 16);
}

// CK-pattern addrspace casts (generic -> AS1 / AS3 via integer).
__device__ __forceinline__ void gload16(const void* g, const void* l) {
  __builtin_amdgcn_global_load_lds(
      (const AS1 void*)(uintptr_t)g,
      (AS3 void*)(unsigned)(uintptr_t)l,
      16, 0, 0);
}

// ---------------------------------------------------------------------------
// Transpose + f32->bf16 convert: src [K][N] f32 (ld=N) -> dst [N][K] bf16 (ld_dst)
// grid (N/32, K/32, Z)
// ---------------------------------------------------------------------------
__global__ __launch_bounds__(256)
void transpose_cvt(const float* __restrict__ src, long long srcZ,
                   unsigned short* __restrict__ dst, long long dstZ, int ld_dst,
                   int K, int N)
{
  __shared__ float t[32][33];
  const int e = blockIdx.z;
  src += (long long)e * srcZ;
  dst += (long long)e * dstZ;
  const int k0 = blockIdx.y * 32, n0 = blockIdx.x * 32;
  const int tx = threadIdx.x & 31, ty = threadIdx.x >> 5;
#pragma unroll
  for (int r = 0; r < 32; r += 8)
    t[ty + r][tx] = src[(long long)(k0 + ty + r) * N + n0 + tx];
  __syncthreads();
#pragma unroll
  for (int r = 0; r < 32; r += 8) {
    const int n = ty + r;
    dst[(long long)(n0 + n) * ld_dst + k0 + tx] = f2bu(t[tx][n]);
  }
}

// ---------------------------------------------------------------------------
// Elementwise f32 -> bf16
// ---------------------------------------------------------------------------
__global__ __launch_bounds__(256)
void cvt_f32_bf16(const float* __restrict__ src, unsigned short* __restrict__ dst, int n)
{
  const int i = (blockIdx.x * 256 + threadIdx.x) * 4;
  if (i >= n) return;
  float4 v = *(const float4*)(src + i);
  ushort4 o;
  o.x = f2bu(v.x); o.y = f2bu(v.y); o.z = f2bu(v.z); o.w = f2bu(v.w);
  *(ushort4*)(dst + i) = o;
}

// ---------------------------------------------------------------------------
// bf16 GEMM, C[m,n] = sum_k A[m,k] * Bt[n,k]   (A: [M][K], Bt: [N][K], both ld=K)
// m97 structure: 128x128 tile, BK=32, 4 waves (2x2), global_load_lds width 16.
// EPI 0: bf16 out = acc + bias[col]                      (QKV)
// EPI 1: bf16 out = gate * gelu_new(acc + bias[col])     (expert h, gate folded)
// EPI 2: f32  out = acc + bias2[(row>>10)*1024 + col]    (final, direct to d_out)
// ---------------------------------------------------------------------------
#define BM 128
#define BN 128
#define BK 32

template<int EPI>
__global__ __launch_bounds__(256)
void gemm_bt(const unsigned short* __restrict__ Aall, long long strideA,
             const unsigned short* __restrict__ Btall, long long strideB,
             const float* __restrict__ biasAll, long long strideBias,
             void* __restrict__ outAll, long long strideOut, int ldo,
             int M, int N, int K,
             const float* __restrict__ gates)
{
  const int z = blockIdx.z;
  const unsigned short* A  = Aall  + (long long)z * strideA;
  const unsigned short* Bt = Btall + (long long)z * strideB;
  const float* bias = biasAll + (long long)z * strideBias;

  __shared__ unsigned short As[BM * BK];
  __shared__ unsigned short Bs[BN * BK];

  const int tid  = threadIdx.x;
  const int lane = tid & 63;
  const int w    = tid >> 6;       // 0..3
  const int wr   = w >> 1;
  const int wc   = w & 1;

  const int m0 = blockIdx.y * BM;
  const int n0 = blockIdx.x * BN;

  v4f acc[4][4] = {};

  const int srow = lane >> 2;       // 0..15
  const int scol = (lane & 3) * 8;  // 0,8,16,24

  const unsigned short* agbase = A  + (long long)(m0 + srow) * K + scol;
  const unsigned short* bgbase = Bt + (long long)(n0 + srow) * K + scol;

  for (int k0 = 0; k0 < K; k0 += BK) {
    __syncthreads();
#pragma unroll
    for (int j = 0; j < 2; ++j) {
      const int c = w * 2 + j;   // chunk 0..7, wave-uniform
      gload16(agbase + (long long)(c * 16) * K + k0, As + c * 512);
      gload16(bgbase + (long long)(c * 16) * K + k0, Bs + c * 512);
    }
    __syncthreads();

    v8s af[4], bfr[4];
#pragma unroll
    for (int i = 0; i < 4; ++i)
      af[i] = *(const v8s*)(As + (wr * 64 + i * 16 + (lane & 15)) * BK + (lane >> 4) * 8);
#pragma unroll
    for (int j = 0; j < 4; ++j)
      bfr[j] = *(const v8s*)(Bs + (wc * 64 + j * 16 + (lane & 15)) * BK + (lane >> 4) * 8);
#pragma unroll
    for (int i = 0; i < 4; ++i)
#pragma unroll
      for (int j = 0; j < 4; ++j)
        acc[i][j] = __builtin_amdgcn_mfma_f32_16x16x32_bf16(af[i], bfr[j], acc[i][j], 0, 0, 0);
  }

  const int row0 = m0 + wr * 64;
  const int col0 = n0 + wc * 64;
  const int lr = (lane >> 4) * 4;
  const int lc = lane & 15;

#pragma unroll
  for (int i = 0; i < 4; ++i) {
#pragma unroll
    for (int r = 0; r < 4; ++r) {
      const int row = row0 + i * 16 + lr + r;
      float gate = 0.f;
      if (EPI == 1) gate = gates[(row >> 10) * 8 + z];
#pragma unroll
      for (int j = 0; j < 4; ++j) {
        const int col = col0 + j * 16 + lc;
        float v = acc[i][j][r];
        if (EPI == 0) {
          v += bias[col];
          ((unsigned short*)outAll)[(long long)z * strideOut + (long long)row * ldo + col] = f2bu(v);
        } else if (EPI == 1) {
          v += bias[col];
          // gelu_new (tanh approx via exp)
          float u = 0.7978845608028654f * (v + 0.044715f * v * v * v);
          u = fminf(fmaxf(u, -15.f), 15.f);
          float e2 = __expf(2.f * u);
          float th = (e2 - 1.f) / (e2 + 1.f);
          float h = 0.5f * v * (1.f + th);
          ((unsigned short*)outAll)[(long long)z * strideOut + (long long)row * ldo + col] = f2bu(gate * h);
        } else {
          ((float*)outAll)[(long long)row * ldo + col] = v + biasAll[(row >> 10) * 1024 + col];
        }
      }
    }
  }
}

// ---------------------------------------------------------------------------
// Per-token cross-head attention. One block (256 thr) per token.
// scores[q,k] = dot64(Q[q],K[k])/8 ; softmax over k ; out = attn @ V
// writes scrambled a: a[b][q*64 + (s>>4)][(s&15)*64 + hd]
// ---------------------------------------------------------------------------
__global__ __launch_bounds__(256)
void attn_kernel(const unsigned short* __restrict__ Qb,
                 const unsigned short* __restrict__ Kb,
                 const unsigned short* __restrict__ Vb,
                 unsigned short* __restrict__ a)
{
  const int token = blockIdx.x;
  const int b = token >> 10, s = token & 1023;
  __shared__ float Qs[16][65], Ks[16][65], Vs[16][65];
  __shared__ float attn_s[16][17];
  const int t = threadIdx.x;
  const long long base = (long long)token * 1024;

  {
    const int i0 = t * 4;
    const int hh = i0 >> 6, dd = i0 & 63;
    ushort4 qv = *(const ushort4*)(Qb + base + i0);
    ushort4 kv = *(const ushort4*)(Kb + base + i0);
    ushort4 vv = *(const ushort4*)(Vb + base + i0);
    Qs[hh][dd+0]=b2f(qv.x); Qs[hh][dd+1]=b2f(qv.y); Qs[hh][dd+2]=b2f(qv.z); Qs[hh][dd+3]=b2f(qv.w);
    Ks[hh][dd+0]=b2f(kv.x); Ks[hh][dd+1]=b2f(kv.y); Ks[hh][dd+2]=b2f(kv.z); Ks[hh][dd+3]=b2f(kv.w);
    Vs[hh][dd+0]=b2f(vv.x); Vs[hh][dd+1]=b2f(vv.y); Vs[hh][dd+2]=b2f(vv.z); Vs[hh][dd+3]=b2f(vv.w);
  }
  __syncthreads();

  const int q = t >> 4, k = t & 15;
  float sc = 0.f;
#pragma unroll
  for (int d = 0; d < 64; ++d) sc += Qs[q][d] * Ks[k][d];
  sc *= 0.125f;
  float mx = sc;
#pragma unroll
  for (int m = 1; m < 16; m <<= 1) mx = fmaxf(mx, __shfl_xor(mx, m, 64));
  float ex = __expf(sc - mx);
  float sum = ex;
#pragma unroll
  for (int m = 1; m < 16; m <<= 1) sum += __shfl_xor(sum, m, 64);
  attn_s[q][k] = ex / sum;
  __syncthreads();

  const int hd = t & 63;
  const int wv = t >> 6;
#pragma unroll
  for (int r = 0; r < 4; ++r) {
    const int qq = wv * 4 + r;
    float o = 0.f;
#pragma unroll
    for (int kk = 0; kk < 16; ++kk) o += attn_s[qq][kk] * Vs[kk][hd];
    a[(long long)b * 1048576 + (long long)(qq * 64 + (s >> 4)) * 1024 + (s & 15) * 64 + hd] = f2bu(o);
  }
}

// ---------------------------------------------------------------------------
// Partial column sums of a (bf16 [4][1024][1024]) -> part [8][4][1024] f32
// grid (16, 8): x = b*4 + dchunk, y = row chunk of 128
// ---------------------------------------------------------------------------
__global__ __launch_bounds__(256)
void col_sum_part(const unsigned short* __restrict__ a, float* __restrict__ part)
{
  const int bx = blockIdx.x;
  const int b = bx >> 2;
  const int d = (bx & 3) * 256 + threadIdx.x;
  const int y = blockIdx.y;
  const unsigned short* p = a + (long long)b * 1048576 + (long long)y * 131072 + d;
  float s = 0.f;
  for (int i = 0; i < 128; ++i) s += b2f(p[i * 1024]);
  part[(y * 4 + b) * 1024 + d] = s;
}

// ---------------------------------------------------------------------------
// gates = softmax(mean(a) @ Wg + bg) ; bias2[b][n] = sum_e gates[b][e]*b2[e][n]
// single block, 256 threads
// ---------------------------------------------------------------------------
__global__ __launch_bounds__(256)
void gates_bias2(const float* __restrict__ part,   // [8][4][1024]
                 const float* __restrict__ Wg,     // [1024][8]
                 const float* __restrict__ bg,     // [8]
                 const float* __restrict__ b2,     // [8][1024]
                 float* __restrict__ gates,        // [4][8]
                 float* __restrict__ bias2)        // [4][1024]
{
  __shared__ float am[4][1024];
  __shared__ float sg[4][8];
  const int t = threadIdx.x;

  for (int i = t; i < 4096; i += 256) {
    const int b = i >> 10, d = i & 1023;
    float s = 0.f;
#pragma unroll
    for (int y = 0; y < 8; ++y) s += part[(y * 4 + b) * 1024 + d];
    am[b][d] = s * (1.f / 1024.f);
  }
  __syncthreads();

  const int pair = t >> 3, subl = t & 7;
  const int b = pair >> 3, e = pair & 7;
  float s = 0.f;
  for (int d = subl * 128; d < subl * 128 + 128; ++d) s += am[b][d] * Wg[d * 8 + e];
#pragma unroll
  for (int m = 1; m < 8; m <<= 1) s += __shfl_xor(s, m, 64);
  if (subl == 0) sg[b][e] = s + bg[e];
  __syncthreads();

  if (t < 4) {
    float mx = -1e30f;
    for (int ee = 0; ee < 8; ++ee) mx = fmaxf(mx, sg[t][ee]);
    float g[8]; float ssum = 0.f;
    for (int ee = 0; ee < 8; ++ee) { g[ee] = __expf(sg[t][ee] - mx); ssum += g[ee]; }
    for (int ee = 0; ee < 8; ++ee) { sg[t][ee] = g[ee] / ssum; gates[t * 8 + ee] = sg[t][ee]; }
  }
  __syncthreads();

  for (int i = t; i < 4096; i += 256) {
    const int bb = i >> 10, n = i & 1023;
    float ss = 0.f;
#pragma unroll
    for (int ee = 0; ee < 8; ++ee) ss += sg[bb][ee] * b2[ee * 1024 + n];
    bias2[i] = ss;
  }
}

// ---------------------------------------------------------------------------
// Host launch
// ---------------------------------------------------------------------------
extern "C" void kernel_launch(void* const* d_in, const int* in_sizes, int n_in,
                              void* d_out, int out_size, void* d_ws, size_t ws_size,
                              hipStream_t stream) {
  const float* x  = (const float*)d_in[0];
  const float* Wq = (const float*)d_in[1];
  const float* bq = (const float*)d_in[2];
  const float* Wk = (const float*)d_in[3];
  const float* bk = (const float*)d_in[4];
  const float* Wv = (const float*)d_in[5];
  const float* bv = (const float*)d_in[6];
  const float* Wg = (const float*)d_in[7];
  const float* bg = (const float*)d_in[8];
  const float* W1 = (const float*)d_in[9];
  const float* b1 = (const float*)d_in[10];
  const float* W2 = (const float*)d_in[11];
  const float* b2 = (const float*)d_in[12];
  float* out = (float*)d_out;

  // ws layout (bytes):
  //   [0, 64M)          phase1: xb(8M) | Wqkvt(6M) | Q,K,V bf16(24M)   -- then reused as hs(64M)
  //   [64M, 72M)        a bf16
  //   [72M .. )         W1t (16M), W2t (16M), smalls
  if (ws_size < (size_t)109300000) return;  // insufficient scratch -> leave output poisoned

  char* ws = (char*)d_ws;
  unsigned short* xb   = (unsigned short*)(ws + 0);
  unsigned short* Wqt  = (unsigned short*)(ws + 8388608);     // Wq/Wk/Wv contiguous, 1M elems each
  unsigned short* Qb   = (unsigned short*)(ws + 14680064);    // Q,K,V contiguous, 4M elems each
  unsigned short* hs   = (unsigned short*)(ws + 0);           // [4096][8192], phase 2
  unsigned short* abuf = (unsigned short*)(ws + 67108864);    // [4096][1024]
  unsigned short* W1t  = (unsigned short*)(ws + 75497472);    // [8][1024][1024]
  unsigned short* W2t  = (unsigned short*)(ws + 92274688);    // [1024][8192]
  float* part  = (float*)(ws + 109051904);                    // [8][4][1024]
  float* gates = (float*)(ws + 109051904 + 131072);           // [4][8]
  float* bias2 = (float*)(ws + 109051904 + 131072 + 512);     // [4][1024]
  float* bqkv  = (float*)(ws + 109051904 + 131072 + 512 + 16384); // [3][1024]

  dim3 tb(256);

  // Weight conversions (transpose to [N][K] bf16)
  transpose_cvt<<<dim3(32,32,1), tb, 0, stream>>>(Wq, 0LL, Wqt,           0LL, 1024, 1024, 1024);
  transpose_cvt<<<dim3(32,32,1), tb, 0, stream>>>(Wk, 0LL, Wqt + 1048576, 0LL, 1024, 1024, 1024);
  transpose_cvt<<<dim3(32,32,1), tb, 0, stream>>>(Wv, 0LL, Wqt + 2097152, 0LL, 1024, 1024, 1024);
  transpose_cvt<<<dim3(32,32,8), tb, 0, stream>>>(W1, 1048576LL, W1t, 1048576LL, 1024, 1024, 1024);
  transpose_cvt<<<dim3(32,32,8), tb, 0, stream>>>(W2, 1048576LL, W2t, 1024LL,    8192, 1024, 1024);
  cvt_f32_bf16<<<4096, tb, 0, stream>>>(x, xb, 4194304);
  hipMemcpyAsync(bqkv,        bq, 4096, hipMemcpyDeviceToDevice, stream);
  hipMemcpyAsync(bqkv + 1024, bk, 4096, hipMemcpyDeviceToDevice, stream);
  hipMemcpyAsync(bqkv + 2048, bv, 4096, hipMemcpyDeviceToDevice, stream);

  // QKV projections (batched z=3)
  gemm_bt<0><<<dim3(8,32,3), tb, 0, stream>>>(xb, 0LL, Wqt, 1048576LL, bqkv, 1024LL,
                                              Qb, 4194304LL, 1024, 4096, 1024, 1024, nullptr);
  // Attention (per token) -> scrambled a
  attn_kernel<<<4096, tb, 0, stream>>>(Qb, Qb + 4194304, Qb + 8388608, abuf);
  // Gating
  col_sum_part<<<dim3(16,8), tb, 0, stream>>>(abuf, part);
  gates_bias2<<<1, tb, 0, stream>>>(part, Wg, bg, b2, gates, bias2);
  // Expert up-proj + gelu + gate fold (batched z=8): hs[m][e*1024+n]
  gemm_bt<1><<<dim3(8,32,8), tb, 0, stream>>>(abuf, 0LL, W1t, 1048576LL, b1, 1024LL,
                                              hs, 1024LL, 8192, 4096, 1024, 1024, gates);
  // Fused expert down-proj + expert-sum: K=8192, writes f32 d_out
  gemm_bt<2><<<dim3(8,32,1), tb, 0, stream>>>(hs, 0LL, W2t, 0LL, bias2, 0LL,
                                              out, 0LL, 1024, 4096, 1024, 8192, nullptr);
}

// Round 2
// 372.626 us; speedup vs baseline: 1.1241x; 1.1241x over previous
//
#include <hip/hip_runtime.h>
#include <stdint.h>

#define AS1 __attribute__((address_space(1)))
#define AS3 __attribute__((address_space(3)))

typedef short v8s __attribute__((ext_vector_type(8)));
typedef float v4f __attribute__((ext_vector_type(4)));

__device__ __forceinline__ float b2f(unsigned short u) {
  return __uint_as_float(((unsigned int)u) << 16);
}
__device__ __forceinline__ unsigned short f2bu(float f) {
  unsigned int u = __float_as_uint(f);
  u += 0x7fffu + ((u >> 16) & 1u);
  return (unsigned short)(u >> 16);
}

// CK-pattern addrspace casts (generic -> AS1 / AS3 via integer).
__device__ __forceinline__ void gload16(const void* g, const void* l) {
  __builtin_amdgcn_global_load_lds(
      (const AS1 void*)(uintptr_t)g,
      (AS3 void*)(unsigned)(uintptr_t)l,
      16, 0, 0);
}

// ---------------------------------------------------------------------------
// Transpose + f32->bf16 convert: src [K][N] f32 (ld=N) -> dst [N][K] bf16 (ld_dst)
// grid (N/32, K/32, Z)
// ---------------------------------------------------------------------------
__global__ __launch_bounds__(256)
void transpose_cvt(const float* __restrict__ src, long long srcZ,
                   unsigned short* __restrict__ dst, long long dstZ, int ld_dst,
                   int K, int N)
{
  __shared__ float t[32][33];
  const int e = blockIdx.z;
  src += (long long)e * srcZ;
  dst += (long long)e * dstZ;
  const int k0 = blockIdx.y * 32, n0 = blockIdx.x * 32;
  const int tx = threadIdx.x & 31, ty = threadIdx.x >> 5;
#pragma unroll
  for (int r = 0; r < 32; r += 8)
    t[ty + r][tx] = src[(long long)(k0 + ty + r) * N + n0 + tx];
  __syncthreads();
#pragma unroll
  for (int r = 0; r < 32; r += 8) {
    const int n = ty + r;
    dst[(long long)(n0 + n) * ld_dst + k0 + tx] = f2bu(t[tx][n]);
  }
}

// ---------------------------------------------------------------------------
// Elementwise f32 -> bf16
// ---------------------------------------------------------------------------
__global__ __launch_bounds__(256)
void cvt_f32_bf16(const float* __restrict__ src, unsigned short* __restrict__ dst, int n)
{
  const int i = (blockIdx.x * 256 + threadIdx.x) * 4;
  if (i >= n) return;
  float4 v = *(const float4*)(src + i);
  ushort4 o;
  o.x = f2bu(v.x); o.y = f2bu(v.y); o.z = f2bu(v.z); o.w = f2bu(v.w);
  *(ushort4*)(dst + i) = o;
}

// ---------------------------------------------------------------------------
// bf16 GEMM, C[m,n] = sum_k A[m,k] * Bt[n,k]   (A: [M][K] ld=K, Bt: [N][K] ld=K)
// m97 structure: 128x128 tile, BK=32, 4 waves (2x2), global_load_lds width 16.
// EPI 0: bf16 out = acc + bias[col]                      (QKV)
// EPI 1: bf16 out = gate * gelu_new(acc + bias[col])     (expert h, gate folded)
// EPI 3: f32 raw partial store; z selects K-chunk [z*kLen, (z+1)*kLen) and
//        output buffer (z==0 -> outAll, z==1 -> out1).   (split-K final GEMM)
// ---------------------------------------------------------------------------
#define BM 128
#define BN 128
#define BK 32

template<int EPI>
__global__ __launch_bounds__(256)
void gemm_bt(const unsigned short* __restrict__ Aall, long long strideA,
             const unsigned short* __restrict__ Btall, long long strideB,
             const float* __restrict__ biasAll, long long strideBias,
             void* __restrict__ outAll, long long strideOut, int ldo,
             int M, int N, int K, int kLen,
             const float* __restrict__ gates,
             float* __restrict__ out1)
{
  const int z = blockIdx.z;
  const unsigned short* A  = Aall  + (long long)z * strideA;
  const unsigned short* Bt = Btall + (long long)z * strideB;
  const float* bias = biasAll + (long long)z * strideBias;

  __shared__ unsigned short As[BM * BK];
  __shared__ unsigned short Bs[BN * BK];

  const int tid  = threadIdx.x;
  const int lane = tid & 63;
  const int w    = tid >> 6;       // 0..3
  const int wr   = w >> 1;
  const int wc   = w & 1;

  const int m0 = blockIdx.y * BM;
  const int n0 = blockIdx.x * BN;

  v4f acc[4][4] = {};

  const int srow = lane >> 2;       // 0..15
  const int scol = (lane & 3) * 8;  // 0,8,16,24

  const unsigned short* agbase = A  + (long long)(m0 + srow) * K + scol;
  const unsigned short* bgbase = Bt + (long long)(n0 + srow) * K + scol;

  const int kStart = (EPI == 3) ? z * kLen : 0;
  const int kEnd   = kStart + kLen;

  for (int k0 = kStart; k0 < kEnd; k0 += BK) {
    __syncthreads();
#pragma unroll
    for (int j = 0; j < 2; ++j) {
      const int c = w * 2 + j;   // chunk 0..7, wave-uniform
      gload16(agbase + (long long)(c * 16) * K + k0, As + c * 512);
      gload16(bgbase + (long long)(c * 16) * K + k0, Bs + c * 512);
    }
    __syncthreads();

    v8s af[4], bfr[4];
#pragma unroll
    for (int i = 0; i < 4; ++i)
      af[i] = *(const v8s*)(As + (wr * 64 + i * 16 + (lane & 15)) * BK + (lane >> 4) * 8);
#pragma unroll
    for (int j = 0; j < 4; ++j)
      bfr[j] = *(const v8s*)(Bs + (wc * 64 + j * 16 + (lane & 15)) * BK + (lane >> 4) * 8);
#pragma unroll
    for (int i = 0; i < 4; ++i)
#pragma unroll
      for (int j = 0; j < 4; ++j)
        acc[i][j] = __builtin_amdgcn_mfma_f32_16x16x32_bf16(af[i], bfr[j], acc[i][j], 0, 0, 0);
  }

  const int row0 = m0 + wr * 64;
  const int col0 = n0 + wc * 64;
  const int lr = (lane >> 4) * 4;
  const int lc = lane & 15;

  float* po = (EPI == 3) ? ((z == 0) ? (float*)outAll : out1) : nullptr;

#pragma unroll
  for (int i = 0; i < 4; ++i) {
#pragma unroll
    for (int r = 0; r < 4; ++r) {
      const int row = row0 + i * 16 + lr + r;
      float gate = 0.f;
      if (EPI == 1) gate = gates[(row >> 10) * 8 + z];
#pragma unroll
      for (int j = 0; j < 4; ++j) {
        const int col = col0 + j * 16 + lc;
        float v = acc[i][j][r];
        if (EPI == 0) {
          v += bias[col];
          ((unsigned short*)outAll)[(long long)z * strideOut + (long long)row * ldo + col] = f2bu(v);
        } else if (EPI == 1) {
          v += bias[col];
          // gelu_new (tanh approx via exp)
          float u = 0.7978845608028654f * (v + 0.044715f * v * v * v);
          u = fminf(fmaxf(u, -15.f), 15.f);
          float e2 = __expf(2.f * u);
          float th = (e2 - 1.f) / (e2 + 1.f);
          float h = 0.5f * v * (1.f + th);
          ((unsigned short*)outAll)[(long long)z * strideOut + (long long)row * ldo + col] = f2bu(gate * h);
        } else {
          po[(long long)row * ldo + col] = v;
        }
      }
    }
  }
}

// ---------------------------------------------------------------------------
// out = p0(out) + p1 + bias2[b][n]   (4M f32 elements, float4 per thread)
// ---------------------------------------------------------------------------
__global__ __launch_bounds__(256)
void reduce_out(float* __restrict__ out, const float* __restrict__ p1,
                const float* __restrict__ bias2)
{
  const int i = (blockIdx.x * 256 + threadIdx.x) * 4;
  const int b = i >> 20;
  const int n = i & 1023;
  float4 a = *(const float4*)(out + i);
  float4 c = *(const float4*)(p1 + i);
  float4 bb = *(const float4*)(bias2 + b * 1024 + n);
  a.x += c.x + bb.x;
  a.y += c.y + bb.y;
  a.z += c.z + bb.z;
  a.w += c.w + bb.w;
  *(float4*)(out + i) = a;
}

// ---------------------------------------------------------------------------
// Per-token cross-head attention. One block (256 thr) per token.
// scores[q,k] = dot64(Q[q],K[k])/8 ; softmax over k ; out = attn @ V
// writes scrambled a: a[b][q*64 + (s>>4)][(s&15)*64 + hd]
// ---------------------------------------------------------------------------
__global__ __launch_bounds__(256)
void attn_kernel(const unsigned short* __restrict__ Qb,
                 const unsigned short* __restrict__ Kb,
                 const unsigned short* __restrict__ Vb,
                 unsigned short* __restrict__ a)
{
  const int token = blockIdx.x;
  const int b = token >> 10, s = token & 1023;
  __shared__ float Qs[16][65], Ks[16][65], Vs[16][65];
  __shared__ float attn_s[16][17];
  const int t = threadIdx.x;
  const long long base = (long long)token * 1024;

  {
    const int i0 = t * 4;
    const int hh = i0 >> 6, dd = i0 & 63;
    ushort4 qv = *(const ushort4*)(Qb + base + i0);
    ushort4 kv = *(const ushort4*)(Kb + base + i0);
    ushort4 vv = *(const ushort4*)(Vb + base + i0);
    Qs[hh][dd+0]=b2f(qv.x); Qs[hh][dd+1]=b2f(qv.y); Qs[hh][dd+2]=b2f(qv.z); Qs[hh][dd+3]=b2f(qv.w);
    Ks[hh][dd+0]=b2f(kv.x); Ks[hh][dd+1]=b2f(kv.y); Ks[hh][dd+2]=b2f(kv.z); Ks[hh][dd+3]=b2f(kv.w);
    Vs[hh][dd+0]=b2f(vv.x); Vs[hh][dd+1]=b2f(vv.y); Vs[hh][dd+2]=b2f(vv.z); Vs[hh][dd+3]=b2f(vv.w);
  }
  __syncthreads();

  const int q = t >> 4, k = t & 15;
  float sc = 0.f;
#pragma unroll
  for (int d = 0; d < 64; ++d) sc += Qs[q][d] * Ks[k][d];
  sc *= 0.125f;
  float mx = sc;
#pragma unroll
  for (int m = 1; m < 16; m <<= 1) mx = fmaxf(mx, __shfl_xor(mx, m, 64));
  float ex = __expf(sc - mx);
  float sum = ex;
#pragma unroll
  for (int m = 1; m < 16; m <<= 1) sum += __shfl_xor(sum, m, 64);
  attn_s[q][k] = ex / sum;
  __syncthreads();

  const int hd = t & 63;
  const int wv = t >> 6;
#pragma unroll
  for (int r = 0; r < 4; ++r) {
    const int qq = wv * 4 + r;
    float o = 0.f;
#pragma unroll
    for (int kk = 0; kk < 16; ++kk) o += attn_s[qq][kk] * Vs[kk][hd];
    a[(long long)b * 1048576 + (long long)(qq * 64 + (s >> 4)) * 1024 + (s & 15) * 64 + hd] = f2bu(o);
  }
}

// ---------------------------------------------------------------------------
// Partial column sums of a (bf16 [4][1024][1024]) -> part [8][4][1024] f32
// grid (16, 8): x = b*4 + dchunk, y = row chunk of 128
// ---------------------------------------------------------------------------
__global__ __launch_bounds__(256)
void col_sum_part(const unsigned short* __restrict__ a, float* __restrict__ part)
{
  const int bx = blockIdx.x;
  const int b = bx >> 2;
  const int d = (bx & 3) * 256 + threadIdx.x;
  const int y = blockIdx.y;
  const unsigned short* p = a + (long long)b * 1048576 + (long long)y * 131072 + d;
  float s = 0.f;
  for (int i = 0; i < 128; ++i) s += b2f(p[i * 1024]);
  part[(y * 4 + b) * 1024 + d] = s;
}

// ---------------------------------------------------------------------------
// gates = softmax(mean(a) @ Wg + bg) ; bias2[b][n] = sum_e gates[b][e]*b2[e][n]
// single block, 256 threads
// ---------------------------------------------------------------------------
__global__ __launch_bounds__(256)
void gates_bias2(const float* __restrict__ part,   // [8][4][1024]
                 const float* __restrict__ Wg,     // [1024][8]
                 const float* __restrict__ bg,     // [8]
                 const float* __restrict__ b2,     // [8][1024]
                 float* __restrict__ gates,        // [4][8]
                 float* __restrict__ bias2)        // [4][1024]
{
  __shared__ float am[4][1024];
  __shared__ float sg[4][8];
  const int t = threadIdx.x;

  for (int i = t; i < 4096; i += 256) {
    const int b = i >> 10, d = i & 1023;
    float s = 0.f;
#pragma unroll
    for (int y = 0; y < 8; ++y) s += part[(y * 4 + b) * 1024 + d];
    am[b][d] = s * (1.f / 1024.f);
  }
  __syncthreads();

  const int pair = t >> 3, subl = t & 7;
  const int b = pair >> 3, e = pair & 7;
  float s = 0.f;
  for (int d = subl * 128; d < subl * 128 + 128; ++d) s += am[b][d] * Wg[d * 8 + e];
#pragma unroll
  for (int m = 1; m < 8; m <<= 1) s += __shfl_xor(s, m, 64);
  if (subl == 0) sg[b][e] = s + bg[e];
  __syncthreads();

  if (t < 4) {
    float mx = -1e30f;
    for (int ee = 0; ee < 8; ++ee) mx = fmaxf(mx, sg[t][ee]);
    float g[8]; float ssum = 0.f;
    for (int ee = 0; ee < 8; ++ee) { g[ee] = __expf(sg[t][ee] - mx); ssum += g[ee]; }
    for (int ee = 0; ee < 8; ++ee) { sg[t][ee] = g[ee] / ssum; gates[t * 8 + ee] = sg[t][ee]; }
  }
  __syncthreads();

  for (int i = t; i < 4096; i += 256) {
    const int bb = i >> 10, n = i & 1023;
    float ss = 0.f;
#pragma unroll
    for (int ee = 0; ee < 8; ++ee) ss += sg[bb][ee] * b2[ee * 1024 + n];
    bias2[i] = ss;
  }
}

// ---------------------------------------------------------------------------
// Host launch
// ---------------------------------------------------------------------------
extern "C" void kernel_launch(void* const* d_in, const int* in_sizes, int n_in,
                              void* d_out, int out_size, void* d_ws, size_t ws_size,
                              hipStream_t stream) {
  const float* x  = (const float*)d_in[0];
  const float* Wq = (const float*)d_in[1];
  const float* bq = (const float*)d_in[2];
  const float* Wk = (const float*)d_in[3];
  const float* bk = (const float*)d_in[4];
  const float* Wv = (const float*)d_in[5];
  const float* bv = (const float*)d_in[6];
  const float* Wg = (const float*)d_in[7];
  const float* bg = (const float*)d_in[8];
  const float* W1 = (const float*)d_in[9];
  const float* b1 = (const float*)d_in[10];
  const float* W2 = (const float*)d_in[11];
  const float* b2 = (const float*)d_in[12];
  float* out = (float*)d_out;

  // ws layout (bytes):
  //   [0, 64M)          phase1: xb(8M) | Wqkvt(6M) | Q,K,V bf16(24M)   -- then reused as hs(64M)
  //   [64M, 72M)        a bf16
  //   [72M .. )         W1t (16M, reused as split-K partial1 f32), W2t (16M), smalls
  if (ws_size < (size_t)109300000) return;  // insufficient scratch -> leave output poisoned

  char* ws = (char*)d_ws;
  unsigned short* xb   = (unsigned short*)(ws + 0);
  unsigned short* Wqt  = (unsigned short*)(ws + 8388608);     // Wq/Wk/Wv contiguous, 1M elems each
  unsigned short* Qb   = (unsigned short*)(ws + 14680064);    // Q,K,V contiguous, 4M elems each
  unsigned short* hs   = (unsigned short*)(ws + 0);           // [4096][8192], phase 2
  unsigned short* abuf = (unsigned short*)(ws + 67108864);    // [4096][1024]
  unsigned short* W1t  = (unsigned short*)(ws + 75497472);    // [8][1024][1024]
  float*          p1   = (float*)(ws + 75497472);             // split-K partial (16MB, reuses W1t)
  unsigned short* W2t  = (unsigned short*)(ws + 92274688);    // [1024][8192]
  float* part  = (float*)(ws + 109051904);                    // [8][4][1024]
  float* gates = (float*)(ws + 109051904 + 131072);           // [4][8]
  float* bias2 = (float*)(ws + 109051904 + 131072 + 512);     // [4][1024]
  float* bqkv  = (float*)(ws + 109051904 + 131072 + 512 + 16384); // [3][1024]

  dim3 tb(256);

  // Weight conversions (transpose to [N][K] bf16)
  transpose_cvt<<<dim3(32,32,1), tb, 0, stream>>>(Wq, 0LL, Wqt,           0LL, 1024, 1024, 1024);
  transpose_cvt<<<dim3(32,32,1), tb, 0, stream>>>(Wk, 0LL, Wqt + 1048576, 0LL, 1024, 1024, 1024);
  transpose_cvt<<<dim3(32,32,1), tb, 0, stream>>>(Wv, 0LL, Wqt + 2097152, 0LL, 1024, 1024, 1024);
  transpose_cvt<<<dim3(32,32,8), tb, 0, stream>>>(W1, 1048576LL, W1t, 1048576LL, 1024, 1024, 1024);
  transpose_cvt<<<dim3(32,32,8), tb, 0, stream>>>(W2, 1048576LL, W2t, 1024LL,    8192, 1024, 1024);
  cvt_f32_bf16<<<4096, tb, 0, stream>>>(x, xb, 4194304);
  hipMemcpyAsync(bqkv,        bq, 4096, hipMemcpyDeviceToDevice, stream);
  hipMemcpyAsync(bqkv + 1024, bk, 4096, hipMemcpyDeviceToDevice, stream);
  hipMemcpyAsync(bqkv + 2048, bv, 4096, hipMemcpyDeviceToDevice, stream);

  // QKV projections (batched z=3)
  gemm_bt<0><<<dim3(8,32,3), tb, 0, stream>>>(xb, 0LL, Wqt, 1048576LL, bqkv, 1024LL,
                                              Qb, 4194304LL, 1024, 4096, 1024, 1024, 1024,
                                              nullptr, nullptr);
  // Attention (per token) -> scrambled a
  attn_kernel<<<4096, tb, 0, stream>>>(Qb, Qb + 4194304, Qb + 8388608, abuf);
  // Gating
  col_sum_part<<<dim3(16,8), tb, 0, stream>>>(abuf, part);
  gates_bias2<<<1, tb, 0, stream>>>(part, Wg, bg, b2, gates, bias2);
  // Expert up-proj + gelu + gate fold (batched z=8): hs[m][e*1024+n]
  gemm_bt<1><<<dim3(8,32,8), tb, 0, stream>>>(abuf, 0LL, W1t, 1048576LL, b1, 1024LL,
                                              hs, 1024LL, 8192, 4096, 1024, 1024, 1024,
                                              gates, nullptr);
  // Fused expert down-proj, split-K x2: z=0 -> out (K 0..4096), z=1 -> p1 (K 4096..8192)
  gemm_bt<3><<<dim3(8,32,2), tb, 0, stream>>>(hs, 0LL, W2t, 0LL, nullptr, 0LL,
                                              out, 0LL, 1024, 4096, 1024, 8192, 4096,
                                              nullptr, p1);
  // out = out + p1 + bias2
  reduce_out<<<4096, tb, 0, stream>>>(out, p1, bias2);
}

// Round 3
// 320.581 us; speedup vs baseline: 1.3066x; 1.1623x over previous
//
#include <hip/hip_runtime.h>
#include <stdint.h>

#define AS1 __attribute__((address_space(1)))
#define AS3 __attribute__((address_space(3)))

typedef short v8s __attribute__((ext_vector_type(8)));
typedef float v4f __attribute__((ext_vector_type(4)));

__device__ __forceinline__ float b2f(unsigned short u) {
  return __uint_as_float(((unsigned int)u) << 16);
}
__device__ __forceinline__ unsigned short f2bu(float f) {
  unsigned int u = __float_as_uint(f);
  u += 0x7fffu + ((u >> 16) & 1u);
  return (unsigned short)(u >> 16);
}

__device__ __forceinline__ void gload16(const void* g, const void* l) {
  __builtin_amdgcn_global_load_lds(
      (const AS1 void*)(uintptr_t)g,
      (AS3 void*)(unsigned)(uintptr_t)l,
      16, 0, 0);
}

#define SB0 __builtin_amdgcn_sched_barrier(0)
#define BAR do { SB0; __builtin_amdgcn_s_barrier(); SB0; } while (0)
#define VMC4 asm volatile("s_waitcnt vmcnt(4)" ::: "memory")
#define VMC0 asm volatile("s_waitcnt vmcnt(0)" ::: "memory")

// ---------------------------------------------------------------------------
// Transpose + f32->bf16 convert: src [K][N] f32 (ld=N) -> dst [N][K] bf16
// ---------------------------------------------------------------------------
__global__ __launch_bounds__(256)
void transpose_cvt(const float* __restrict__ src, long long srcZ,
                   unsigned short* __restrict__ dst, long long dstZ, int ld_dst,
                   int K, int N)
{
  __shared__ float t[32][33];
  const int e = blockIdx.z;
  src += (long long)e * srcZ;
  dst += (long long)e * dstZ;
  const int k0 = blockIdx.y * 32, n0 = blockIdx.x * 32;
  const int tx = threadIdx.x & 31, ty = threadIdx.x >> 5;
#pragma unroll
  for (int r = 0; r < 32; r += 8)
    t[ty + r][tx] = src[(long long)(k0 + ty + r) * N + n0 + tx];
  __syncthreads();
#pragma unroll
  for (int r = 0; r < 32; r += 8) {
    const int n = ty + r;
    dst[(long long)(n0 + n) * ld_dst + k0 + tx] = f2bu(t[tx][n]);
  }
}

__global__ __launch_bounds__(256)
void cvt_f32_bf16(const float* __restrict__ src, unsigned short* __restrict__ dst, int n)
{
  const int i = (blockIdx.x * 256 + threadIdx.x) * 4;
  if (i >= n) return;
  float4 v = *(const float4*)(src + i);
  ushort4 o;
  o.x = f2bu(v.x); o.y = f2bu(v.y); o.z = f2bu(v.z); o.w = f2bu(v.w);
  *(ushort4*)(dst + i) = o;
}

// ---------------------------------------------------------------------------
// 256x256 8-phase bf16 GEMM (T2-lite + T3 + T4 + T5), BK=64, 8 waves (2Mx4N).
// C[m,n] = sum_k A[m,k]*Bt[n,k].  A:[M][lda], Bt:[N][ldb].
// EPI 0: bf16 Q/K/V out = acc + bias[col]; out slab = col>>10
// EPI 1: bf16 out = gate * gelu_new(acc + bias[col])  (hs, ld 8192)
// EPI 3: split-K partial: z=0 -> f32 out0, z>0 -> bf16 pbs[z-1]
// ---------------------------------------------------------------------------
template<int MH, int NH>
__device__ __forceinline__ void quad_read(v8s af[4][2], v8s bf[2][2],
    const unsigned short* pa, const unsigned short* pb,
    int wm, int wn, int rr, int rc0)
{
#pragma unroll
  for (int i = 0; i < 4; ++i)
#pragma unroll
    for (int s = 0; s < 2; ++s)
      af[i][s] = *(const v8s*)(pa + MH*8192 + (wm*64 + i*16 + rr)*64 + s*32 + rc0);
#pragma unroll
  for (int j = 0; j < 2; ++j)
#pragma unroll
    for (int s = 0; s < 2; ++s)
      bf[j][s] = *(const v8s*)(pb + NH*8192 + (wn*32 + j*16 + rr)*64 + s*32 + rc0);
}

template<int MH, int NH>
__device__ __forceinline__ void quad_mfma(v4f acc[8][4], v8s af[4][2], v8s bf[2][2])
{
  __builtin_amdgcn_s_setprio(1);
#pragma unroll
  for (int i = 0; i < 4; ++i)
#pragma unroll
    for (int j = 0; j < 2; ++j)
#pragma unroll
      for (int s = 0; s < 2; ++s)
        acc[MH*4+i][NH*2+j] = __builtin_amdgcn_mfma_f32_16x16x32_bf16(
            af[i][s], bf[j][s], acc[MH*4+i][NH*2+j], 0, 0, 0);
  __builtin_amdgcn_s_setprio(0);
}

// stage one 128-row half-tile (2 x gload16 per thread)
#define STAGE(G, LD, LDSBASE, GROW0, KT) do { \
    gload16((G) + (long long)((GROW0) + sRow) * (LD) + (KT) + sK, \
            (LDSBASE) + (w*8)*64); \
    gload16((G) + (long long)((GROW0) + 64 + sRow) * (LD) + (KT) + sK, \
            (LDSBASE) + (64 + w*8)*64); \
  } while (0)

template<int EPI>
__global__ __launch_bounds__(512, 2)
void gemm256(const unsigned short* __restrict__ A, int lda,
             const unsigned short* __restrict__ Bt, int ldb,
             const float* __restrict__ bias,
             void* __restrict__ out0, unsigned short* __restrict__ pbs,
             int kLen, const float* __restrict__ gates)
{
  __shared__ __align__(16) unsigned short lds[65536];   // 128 KiB
  unsigned short* As0 = lds;
  unsigned short* As1 = lds + 16384;
  unsigned short* Bs0 = lds + 32768;
  unsigned short* Bs1 = lds + 49152;

  const int tid  = threadIdx.x;
  const int lane = tid & 63;
  const int w    = tid >> 6;        // 0..7
  const int wm   = w >> 2;          // 0..1
  const int wn   = w & 3;           // 0..3
  const int m0   = blockIdx.y * 256;
  const int n0   = blockIdx.x * 256;
  const int z    = blockIdx.z;
  const int kBase = (EPI == 3) ? z * kLen : 0;

  // staging constants: dest row = w*8 + (lane>>3); src k pre-swizzled (rule 21)
  const int sRow = w*8 + (lane >> 3);
  const int sK   = ((lane & 7) * 8) ^ ((lane >> 1) & 24);
  // read constants: row = ... + (lane&15); col ^= (row&6)<<2
  const int rr   = lane & 15;
  const int rc0  = (((lane >> 4) * 8) ^ ((lane & 6) << 2));

  v4f acc[8][4] = {};
  v8s af[4][2], bf[2][2];

  const int iters = kLen >> 7;   // 2 K-tiles (BK=64) per iteration

  // ---- prologue: buf0 <- tile0 (all), buf1 <- tile1 (A-lo, B-lo) ----
  STAGE(A,  lda, As0,        m0,       kBase);
  STAGE(A,  lda, As0 + 8192, m0 + 128, kBase);
  STAGE(Bt, ldb, Bs0,        n0,       kBase);
  STAGE(Bt, ldb, Bs0 + 8192, n0 + 128, kBase);
  STAGE(A,  lda, As1,        m0,       kBase + 64);
  STAGE(Bt, ldb, Bs1,        n0,       kBase + 64);
  VMC4;   // tile0 landed; tile1 A-lo/B-lo (4 loads) in flight
  BAR;

  for (int it = 0; it < iters; ++it) {
    const bool nl = (it != iters - 1);
    const int kT1 = kBase + (2*it + 1) * 64;
    const int kT2 = kT1 + 64;
    const int kT3 = kT1 + 128;

    // ph1: Q(0,0) buf0 | stage buf1.A-hi(T+1)
    quad_read<0,0>(af, bf, As0, Bs0, wm, wn, rr, rc0);
    STAGE(A, lda, As1 + 8192, m0 + 128, kT1);
    BAR; quad_mfma<0,0>(acc, af, bf); BAR;
    // ph2: Q(0,1) buf0 | stage buf1.B-hi(T+1)
    quad_read<0,1>(af, bf, As0, Bs0, wm, wn, rr, rc0);
    STAGE(Bt, ldb, Bs1 + 8192, n0 + 128, kT1);
    BAR; quad_mfma<0,1>(acc, af, bf); BAR;
    // ph3: Q(1,0) buf0 | stage buf0.A-lo(T+2)
    quad_read<1,0>(af, bf, As0, Bs0, wm, wn, rr, rc0);
    if (nl) STAGE(A, lda, As0, m0, kT2);
    BAR; quad_mfma<1,0>(acc, af, bf); BAR;
    // ph4: Q(1,1) buf0 | stage buf0.B-lo(T+2) | vmcnt: buf1(T+1) complete
    quad_read<1,1>(af, bf, As0, Bs0, wm, wn, rr, rc0);
    if (nl) STAGE(Bt, ldb, Bs0, n0, kT2);
    BAR; quad_mfma<1,1>(acc, af, bf);
    if (nl) { VMC4; } else { VMC0; }
    BAR;
    // ph5: Q(0,0) buf1 | stage buf0.A-hi(T+2)
    quad_read<0,0>(af, bf, As1, Bs1, wm, wn, rr, rc0);
    if (nl) STAGE(A, lda, As0 + 8192, m0 + 128, kT2);
    BAR; quad_mfma<0,0>(acc, af, bf); BAR;
    // ph6: Q(0,1) buf1 | stage buf0.B-hi(T+2)
    quad_read<0,1>(af, bf, As1, Bs1, wm, wn, rr, rc0);
    if (nl) STAGE(Bt, ldb, Bs0 + 8192, n0 + 128, kT2);
    BAR; quad_mfma<0,1>(acc, af, bf); BAR;
    // ph7: Q(1,0) buf1 | stage buf1.A-lo(T+3)
    quad_read<1,0>(af, bf, As1, Bs1, wm, wn, rr, rc0);
    if (nl) STAGE(A, lda, As1, m0, kT3);
    BAR; quad_mfma<1,0>(acc, af, bf); BAR;
    // ph8: Q(1,1) buf1 | stage buf1.B-lo(T+3) | vmcnt: buf0(T+2) complete
    quad_read<1,1>(af, bf, As1, Bs1, wm, wn, rr, rc0);
    if (nl) STAGE(Bt, ldb, Bs1, n0, kT3);
    BAR; quad_mfma<1,1>(acc, af, bf);
    if (nl) { VMC4; } else { VMC0; }
    BAR;
  }

  // ---- epilogue ----
  const int lr4 = (lane >> 4) * 4;
  const int lc  = lane & 15;
  float gate = 0.f;
  if (EPI == 1) gate = gates[(m0 >> 10) * 8 + (n0 >> 10)];

#pragma unroll
  for (int mi = 0; mi < 8; ++mi) {
    const int rowb = m0 + (mi >> 2) * 128 + wm * 64 + (mi & 3) * 16 + lr4;
#pragma unroll
    for (int nj = 0; nj < 4; ++nj) {
      const int col = n0 + (nj >> 1) * 128 + wn * 32 + (nj & 1) * 16 + lc;
#pragma unroll
      for (int r = 0; r < 4; ++r) {
        const int row = rowb + r;
        float v = acc[mi][nj][r];
        if (EPI == 0) {
          v += bias[col];
          const int which = col >> 10;
          ((unsigned short*)out0)[(long long)which * 4194304 + (long long)row * 1024 + (col & 1023)] = f2bu(v);
        } else if (EPI == 1) {
          v += bias[col];
          float u = 0.7978845608028654f * (v + 0.044715f * v * v * v);
          u = fminf(fmaxf(u, -15.f), 15.f);
          float e2 = __expf(2.f * u);
          float th = (e2 - 1.f) / (e2 + 1.f);
          ((unsigned short*)out0)[(long long)row * 8192 + col] = f2bu(gate * 0.5f * v * (1.f + th));
        } else {
          if (z == 0) ((float*)out0)[(long long)row * 1024 + col] = v;
          else pbs[(long long)(z - 1) * 4194304 + (long long)row * 1024 + col] = f2bu(v);
        }
      }
    }
  }
}

// ---------------------------------------------------------------------------
// out = out + pb0 + pb1 + pb2 (bf16 partials) + bias2[b][n]
// ---------------------------------------------------------------------------
__global__ __launch_bounds__(256)
void reduce3(float* __restrict__ out, const unsigned short* __restrict__ pb,
             const float* __restrict__ bias2)
{
  const int i = (blockIdx.x * 256 + threadIdx.x) * 4;
  const int b = i >> 20;
  const int n = i & 1023;
  float4 a = *(const float4*)(out + i);
  ushort4 p0 = *(const ushort4*)(pb + i);
  ushort4 p1 = *(const ushort4*)(pb + 4194304 + i);
  ushort4 p2 = *(const ushort4*)(pb + 8388608 + i);
  float4 bb = *(const float4*)(bias2 + b * 1024 + n);
  a.x += b2f(p0.x) + b2f(p1.x) + b2f(p2.x) + bb.x;
  a.y += b2f(p0.y) + b2f(p1.y) + b2f(p2.y) + bb.y;
  a.z += b2f(p0.z) + b2f(p1.z) + b2f(p2.z) + bb.z;
  a.w += b2f(p0.w) + b2f(p1.w) + b2f(p2.w) + bb.w;
  *(float4*)(out + i) = a;
}

// ---------------------------------------------------------------------------
// Per-token cross-head attention (unchanged)
// ---------------------------------------------------------------------------
__global__ __launch_bounds__(256)
void attn_kernel(const unsigned short* __restrict__ Qb,
                 const unsigned short* __restrict__ Kb,
                 const unsigned short* __restrict__ Vb,
                 unsigned short* __restrict__ a)
{
  const int token = blockIdx.x;
  const int b = token >> 10, s = token & 1023;
  __shared__ float Qs[16][65], Ks[16][65], Vs[16][65];
  __shared__ float attn_s[16][17];
  const int t = threadIdx.x;
  const long long base = (long long)token * 1024;

  {
    const int i0 = t * 4;
    const int hh = i0 >> 6, dd = i0 & 63;
    ushort4 qv = *(const ushort4*)(Qb + base + i0);
    ushort4 kv = *(const ushort4*)(Kb + base + i0);
    ushort4 vv = *(const ushort4*)(Vb + base + i0);
    Qs[hh][dd+0]=b2f(qv.x); Qs[hh][dd+1]=b2f(qv.y); Qs[hh][dd+2]=b2f(qv.z); Qs[hh][dd+3]=b2f(qv.w);
    Ks[hh][dd+0]=b2f(kv.x); Ks[hh][dd+1]=b2f(kv.y); Ks[hh][dd+2]=b2f(kv.z); Ks[hh][dd+3]=b2f(kv.w);
    Vs[hh][dd+0]=b2f(vv.x); Vs[hh][dd+1]=b2f(vv.y); Vs[hh][dd+2]=b2f(vv.z); Vs[hh][dd+3]=b2f(vv.w);
  }
  __syncthreads();

  const int q = t >> 4, k = t & 15;
  float sc = 0.f;
#pragma unroll
  for (int d = 0; d < 64; ++d) sc += Qs[q][d] * Ks[k][d];
  sc *= 0.125f;
  float mx = sc;
#pragma unroll
  for (int m = 1; m < 16; m <<= 1) mx = fmaxf(mx, __shfl_xor(mx, m, 64));
  float ex = __expf(sc - mx);
  float sum = ex;
#pragma unroll
  for (int m = 1; m < 16; m <<= 1) sum += __shfl_xor(sum, m, 64);
  attn_s[q][k] = ex / sum;
  __syncthreads();

  const int hd = t & 63;
  const int wv = t >> 6;
#pragma unroll
  for (int r = 0; r < 4; ++r) {
    const int qq = wv * 4 + r;
    float o = 0.f;
#pragma unroll
    for (int kk = 0; kk < 16; ++kk) o += attn_s[qq][kk] * Vs[kk][hd];
    a[(long long)b * 1048576 + (long long)(qq * 64 + (s >> 4)) * 1024 + (s & 15) * 64 + hd] = f2bu(o);
  }
}

// ---------------------------------------------------------------------------
// Gating helpers (unchanged)
// ---------------------------------------------------------------------------
__global__ __launch_bounds__(256)
void col_sum_part(const unsigned short* __restrict__ a, float* __restrict__ part)
{
  const int bx = blockIdx.x;
  const int b = bx >> 2;
  const int d = (bx & 3) * 256 + threadIdx.x;
  const int y = blockIdx.y;
  const unsigned short* p = a + (long long)b * 1048576 + (long long)y * 131072 + d;
  float s = 0.f;
  for (int i = 0; i < 128; ++i) s += b2f(p[i * 1024]);
  part[(y * 4 + b) * 1024 + d] = s;
}

__global__ __launch_bounds__(256)
void gates_bias2(const float* __restrict__ part,
                 const float* __restrict__ Wg,
                 const float* __restrict__ bg,
                 const float* __restrict__ b2,
                 float* __restrict__ gates,
                 float* __restrict__ bias2)
{
  __shared__ float am[4][1024];
  __shared__ float sg[4][8];
  const int t = threadIdx.x;

  for (int i = t; i < 4096; i += 256) {
    const int b = i >> 10, d = i & 1023;
    float s = 0.f;
#pragma unroll
    for (int y = 0; y < 8; ++y) s += part[(y * 4 + b) * 1024 + d];
    am[b][d] = s * (1.f / 1024.f);
  }
  __syncthreads();

  const int pair = t >> 3, subl = t & 7;
  const int b = pair >> 3, e = pair & 7;
  float s = 0.f;
  for (int d = subl * 128; d < subl * 128 + 128; ++d) s += am[b][d] * Wg[d * 8 + e];
#pragma unroll
  for (int m = 1; m < 8; m <<= 1) s += __shfl_xor(s, m, 64);
  if (subl == 0) sg[b][e] = s + bg[e];
  __syncthreads();

  if (t < 4) {
    float mx = -1e30f;
    for (int ee = 0; ee < 8; ++ee) mx = fmaxf(mx, sg[t][ee]);
    float g[8]; float ssum = 0.f;
    for (int ee = 0; ee < 8; ++ee) { g[ee] = __expf(sg[t][ee] - mx); ssum += g[ee]; }
    for (int ee = 0; ee < 8; ++ee) { sg[t][ee] = g[ee] / ssum; gates[t * 8 + ee] = sg[t][ee]; }
  }
  __syncthreads();

  for (int i = t; i < 4096; i += 256) {
    const int bb = i >> 10, n = i & 1023;
    float ss = 0.f;
#pragma unroll
    for (int ee = 0; ee < 8; ++ee) ss += sg[bb][ee] * b2[ee * 1024 + n];
    bias2[i] = ss;
  }
}

// ---------------------------------------------------------------------------
// Host launch
// ---------------------------------------------------------------------------
extern "C" void kernel_launch(void* const* d_in, const int* in_sizes, int n_in,
                              void* d_out, int out_size, void* d_ws, size_t ws_size,
                              hipStream_t stream) {
  const float* x  = (const float*)d_in[0];
  const float* Wq = (const float*)d_in[1];
  const float* bq = (const float*)d_in[2];
  const float* Wk = (const float*)d_in[3];
  const float* bk = (const float*)d_in[4];
  const float* Wv = (const float*)d_in[5];
  const float* bv = (const float*)d_in[6];
  const float* Wg = (const float*)d_in[7];
  const float* bg = (const float*)d_in[8];
  const float* W1 = (const float*)d_in[9];
  const float* b1 = (const float*)d_in[10];
  const float* W2 = (const float*)d_in[11];
  const float* b2 = (const float*)d_in[12];
  float* out = (float*)d_out;

  if (ws_size < (size_t)109300000) return;

  char* ws = (char*)d_ws;
  unsigned short* xb   = (unsigned short*)(ws + 0);
  unsigned short* Wqt  = (unsigned short*)(ws + 8388608);     // [3072][1024]
  unsigned short* Qb   = (unsigned short*)(ws + 14680064);    // Q,K,V [3][4096][1024]
  unsigned short* hs   = (unsigned short*)(ws + 0);           // [4096][8192]
  unsigned short* abuf = (unsigned short*)(ws + 67108864);    // [4096][1024]
  unsigned short* pbs  = (unsigned short*)(ws + 67108864);    // 3x[4096][1024] bf16 (after EPI1)
  unsigned short* W1t  = (unsigned short*)(ws + 75497472);    // [8192][1024]
  unsigned short* W2t  = (unsigned short*)(ws + 92274688);    // [1024][8192]
  float* part  = (float*)(ws + 109051904);
  float* gates = (float*)(ws + 109051904 + 131072);
  float* bias2 = (float*)(ws + 109051904 + 131072 + 512);
  float* bqkv  = (float*)(ws + 109051904 + 131072 + 512 + 16384);

  dim3 tb(256);

  transpose_cvt<<<dim3(32,32,1), tb, 0, stream>>>(Wq, 0LL, Wqt,           0LL, 1024, 1024, 1024);
  transpose_cvt<<<dim3(32,32,1), tb, 0, stream>>>(Wk, 0LL, Wqt + 1048576, 0LL, 1024, 1024, 1024);
  transpose_cvt<<<dim3(32,32,1), tb, 0, stream>>>(Wv, 0LL, Wqt + 2097152, 0LL, 1024, 1024, 1024);
  transpose_cvt<<<dim3(32,32,8), tb, 0, stream>>>(W1, 1048576LL, W1t, 1048576LL, 1024, 1024, 1024);
  transpose_cvt<<<dim3(32,32,8), tb, 0, stream>>>(W2, 1048576LL, W2t, 1024LL,    8192, 1024, 1024);
  cvt_f32_bf16<<<4096, tb, 0, stream>>>(x, xb, 4194304);
  hipMemcpyAsync(bqkv,        bq, 4096, hipMemcpyDeviceToDevice, stream);
  hipMemcpyAsync(bqkv + 1024, bk, 4096, hipMemcpyDeviceToDevice, stream);
  hipMemcpyAsync(bqkv + 2048, bv, 4096, hipMemcpyDeviceToDevice, stream);

  // QKV: M=4096, N=3072 (flat), K=1024
  gemm256<0><<<dim3(12,16,1), 512, 0, stream>>>(xb, 1024, Wqt, 1024, bqkv,
                                                Qb, nullptr, 1024, nullptr);
  // Attention -> scrambled a
  attn_kernel<<<4096, tb, 0, stream>>>(Qb, Qb + 4194304, Qb + 8388608, abuf);
  // Gating
  col_sum_part<<<dim3(16,8), tb, 0, stream>>>(abuf, part);
  gates_bias2<<<1, tb, 0, stream>>>(part, Wg, bg, b2, gates, bias2);
  // Expert up-proj + gelu + gate: M=4096, N=8192 (flat experts), K=1024
  gemm256<1><<<dim3(32,16,1), 512, 0, stream>>>(abuf, 1024, W1t, 1024, b1,
                                                hs, nullptr, 1024, gates);
  // Final down-proj: M=4096, N=1024, K=8192, split-K 4 (z=0 -> out f32, z>0 -> bf16 partials)
  gemm256<3><<<dim3(4,16,4), 512, 0, stream>>>(hs, 8192, W2t, 8192, nullptr,
                                               out, pbs, 2048, nullptr);
  reduce3<<<4096, tb, 0, stream>>>(out, pbs, bias2);
}

// Round 4
// 284.072 us; speedup vs baseline: 1.4745x; 1.1285x over previous
//
#include <hip/hip_runtime.h>
#include <stdint.h>

#define AS1 __attribute__((address_space(1)))
#define AS3 __attribute__((address_space(3)))

typedef short v8s __attribute__((ext_vector_type(8)));
typedef float v4f __attribute__((ext_vector_type(4)));

__device__ __forceinline__ float b2f(unsigned short u) {
  return __uint_as_float(((unsigned int)u) << 16);
}
__device__ __forceinline__ unsigned short f2bu(float f) {
  unsigned int u = __float_as_uint(f);
  u += 0x7fffu + ((u >> 16) & 1u);
  return (unsigned short)(u >> 16);
}

__device__ __forceinline__ void gload16(const void* g, const void* l) {
  __builtin_amdgcn_global_load_lds(
      (const AS1 void*)(uintptr_t)g,
      (AS3 void*)(unsigned)(uintptr_t)l,
      16, 0, 0);
}

#define SB0 __builtin_amdgcn_sched_barrier(0)
#define BAR do { SB0; __builtin_amdgcn_s_barrier(); SB0; } while (0)
#define VMC4 asm volatile("s_waitcnt vmcnt(4)" ::: "memory")
#define VMC0 asm volatile("s_waitcnt vmcnt(0)" ::: "memory")

// ---------------------------------------------------------------------------
// Transpose + f32->bf16 convert: src [K][N] f32 (ld=N) -> dst [N][K] bf16
// ---------------------------------------------------------------------------
__global__ __launch_bounds__(256)
void transpose_cvt(const float* __restrict__ src, long long srcZ,
                   unsigned short* __restrict__ dst, long long dstZ, int ld_dst,
                   int K, int N)
{
  __shared__ float t[32][33];
  const int e = blockIdx.z;
  src += (long long)e * srcZ;
  dst += (long long)e * dstZ;
  const int k0 = blockIdx.y * 32, n0 = blockIdx.x * 32;
  const int tx = threadIdx.x & 31, ty = threadIdx.x >> 5;
#pragma unroll
  for (int r = 0; r < 32; r += 8)
    t[ty + r][tx] = src[(long long)(k0 + ty + r) * N + n0 + tx];
  __syncthreads();
#pragma unroll
  for (int r = 0; r < 32; r += 8) {
    const int n = ty + r;
    dst[(long long)(n0 + n) * ld_dst + k0 + tx] = f2bu(t[tx][n]);
  }
}

__global__ __launch_bounds__(256)
void cvt_f32_bf16(const float* __restrict__ src, unsigned short* __restrict__ dst, int n)
{
  const int i = (blockIdx.x * 256 + threadIdx.x) * 4;
  if (i >= n) return;
  float4 v = *(const float4*)(src + i);
  ushort4 o;
  o.x = f2bu(v.x); o.y = f2bu(v.y); o.z = f2bu(v.z); o.w = f2bu(v.w);
  *(ushort4*)(dst + i) = o;
}

// ---------------------------------------------------------------------------
// 256x256 8-phase bf16 GEMM (T2 st_16x32 + T3 + T4 + T5), BK=64, 8 waves.
// LDS half-tile layout: SUBTILED [row/16][col/32][16][32] elems, 1024B each,
// with st_16x32 swizzle: byte ^= ((byte>>9)&1)<<5  (within each subtile).
// Staging: linear gload dest (1 subtile per gload16); source col pre-swizzled.
// EPI 0: bf16 Q/K/V out = acc + bias[col]; out slab = col>>10
// EPI 1: bf16 out = gate * gelu_new(acc + bias[col])  (hs, ld 8192)
// EPI 3: split-K partial: z=0 -> f32 out0, z>0 -> bf16 pbs[z-1]
// ---------------------------------------------------------------------------
template<int MH, int NH>
__device__ __forceinline__ void quad_read(v8s af[4][2], v8s bf[2][2],
    const unsigned short* pa, const unsigned short* pb,
    int wm, int wn, int rswz)
{
#pragma unroll
  for (int i = 0; i < 4; ++i)
#pragma unroll
    for (int s = 0; s < 2; ++s)
      af[i][s] = *(const v8s*)(pa + MH*8192 + ((((wm*4 + i)*2 + s) << 9) | rswz));
#pragma unroll
  for (int j = 0; j < 2; ++j)
#pragma unroll
    for (int s = 0; s < 2; ++s)
      bf[j][s] = *(const v8s*)(pb + NH*8192 + ((((wn*2 + j)*2 + s) << 9) | rswz));
}

template<int MH, int NH>
__device__ __forceinline__ void quad_mfma(v4f acc[8][4], v8s af[4][2], v8s bf[2][2])
{
  __builtin_amdgcn_s_setprio(1);
#pragma unroll
  for (int i = 0; i < 4; ++i)
#pragma unroll
    for (int j = 0; j < 2; ++j)
#pragma unroll
      for (int s = 0; s < 2; ++s)
        acc[MH*4+i][NH*2+j] = __builtin_amdgcn_mfma_f32_16x16x32_bf16(
            af[i][s], bf[j][s], acc[MH*4+i][NH*2+j], 0, 0, 0);
  __builtin_amdgcn_s_setprio(0);
}

// stage one 128-row half-tile (2 x gload16 per thread, 1 subtile each)
#define STAGE(G, LD, LDSBASE, GROW0, KT) do { \
    gload16((G) + (long long)((GROW0) + sRow) * (LD) + (KT) + sCol, \
            (LDSBASE) + w*512); \
    gload16((G) + (long long)((GROW0) + 64 + sRow) * (LD) + (KT) + sCol, \
            (LDSBASE) + 4096 + w*512); \
  } while (0)

template<int EPI>
__global__ __launch_bounds__(512, 2)
void gemm256(const unsigned short* __restrict__ A, int lda,
             const unsigned short* __restrict__ Bt, int ldb,
             const float* __restrict__ bias,
             void* __restrict__ out0, unsigned short* __restrict__ pbs,
             int kLen, const float* __restrict__ gates)
{
  __shared__ __align__(16) unsigned short lds[65536];   // 128 KiB
  unsigned short* As0 = lds;
  unsigned short* As1 = lds + 16384;
  unsigned short* Bs0 = lds + 32768;
  unsigned short* Bs1 = lds + 49152;

  const int tid  = threadIdx.x;
  const int lane = tid & 63;
  const int w    = tid >> 6;        // 0..7
  const int wm   = w >> 2;          // 0..1
  const int wn   = w & 3;           // 0..3
  const int m0   = blockIdx.y * 256;
  const int n0   = blockIdx.x * 256;
  const int z    = blockIdx.z;
  const int kBase = (EPI == 3) ? z * kLen : 0;

  // staging (subtile w at g=0, subtile 8+w at g=1): lane l fills 16B at l*16
  // source row/col inverse-swizzled (st_16x32: byte^=((byte>>9)&1)<<5)
  const int sRow = (w >> 1) * 16 + (lane >> 2);
  const int sCol = (w & 1) * 32 + (((lane & 3) * 8) ^ (((lane >> 5) & 1) << 4));
  // read: row-in-subtile rr, k-group kgrp; swizzled within-subtile elem offset
  const int rr   = lane & 15;
  const int kgrp = lane >> 4;
  const int rswz = (rr * 32 + kgrp * 8) ^ ((rr & 8) << 1);

  v4f acc[8][4] = {};
  v8s af[4][2], bf[2][2];

  const int iters = kLen >> 7;   // 2 K-tiles (BK=64) per iteration

  // ---- prologue: buf0 <- tile0 (all), buf1 <- tile1 (A-lo, B-lo) ----
  STAGE(A,  lda, As0,        m0,       kBase);
  STAGE(A,  lda, As0 + 8192, m0 + 128, kBase);
  STAGE(Bt, ldb, Bs0,        n0,       kBase);
  STAGE(Bt, ldb, Bs0 + 8192, n0 + 128, kBase);
  STAGE(A,  lda, As1,        m0,       kBase + 64);
  STAGE(Bt, ldb, Bs1,        n0,       kBase + 64);
  VMC4;   // tile0 landed; tile1 A-lo/B-lo (4 loads) in flight
  BAR;

  for (int it = 0; it < iters; ++it) {
    const bool nl = (it != iters - 1);
    const int kT1 = kBase + (2*it + 1) * 64;
    const int kT2 = kT1 + 64;
    const int kT3 = kT1 + 128;

    // ph1: Q(0,0) buf0 | stage buf1.A-hi(T+1)
    quad_read<0,0>(af, bf, As0, Bs0, wm, wn, rswz);
    STAGE(A, lda, As1 + 8192, m0 + 128, kT1);
    BAR; quad_mfma<0,0>(acc, af, bf); BAR;
    // ph2: Q(0,1) buf0 | stage buf1.B-hi(T+1)
    quad_read<0,1>(af, bf, As0, Bs0, wm, wn, rswz);
    STAGE(Bt, ldb, Bs1 + 8192, n0 + 128, kT1);
    BAR; quad_mfma<0,1>(acc, af, bf); BAR;
    // ph3: Q(1,0) buf0 | stage buf0.A-lo(T+2)
    quad_read<1,0>(af, bf, As0, Bs0, wm, wn, rswz);
    if (nl) STAGE(A, lda, As0, m0, kT2);
    BAR; quad_mfma<1,0>(acc, af, bf); BAR;
    // ph4: Q(1,1) buf0 | stage buf0.B-lo(T+2) | vmcnt: buf1(T+1) complete
    quad_read<1,1>(af, bf, As0, Bs0, wm, wn, rswz);
    if (nl) STAGE(Bt, ldb, Bs0, n0, kT2);
    BAR; quad_mfma<1,1>(acc, af, bf);
    if (nl) { VMC4; } else { VMC0; }
    BAR;
    // ph5: Q(0,0) buf1 | stage buf0.A-hi(T+2)
    quad_read<0,0>(af, bf, As1, Bs1, wm, wn, rswz);
    if (nl) STAGE(A, lda, As0 + 8192, m0 + 128, kT2);
    BAR; quad_mfma<0,0>(acc, af, bf); BAR;
    // ph6: Q(0,1) buf1 | stage buf0.B-hi(T+2)
    quad_read<0,1>(af, bf, As1, Bs1, wm, wn, rswz);
    if (nl) STAGE(Bt, ldb, Bs0 + 8192, n0 + 128, kT2);
    BAR; quad_mfma<0,1>(acc, af, bf); BAR;
    // ph7: Q(1,0) buf1 | stage buf1.A-lo(T+3)
    quad_read<1,0>(af, bf, As1, Bs1, wm, wn, rswz);
    if (nl) STAGE(A, lda, As1, m0, kT3);
    BAR; quad_mfma<1,0>(acc, af, bf); BAR;
    // ph8: Q(1,1) buf1 | stage buf1.B-lo(T+3) | vmcnt: buf0(T+2) complete
    quad_read<1,1>(af, bf, As1, Bs1, wm, wn, rswz);
    if (nl) STAGE(Bt, ldb, Bs1, n0, kT3);
    BAR; quad_mfma<1,1>(acc, af, bf);
    if (nl) { VMC4; } else { VMC0; }
    BAR;
  }

  // ---- epilogue ----
  const int lr4 = (lane >> 4) * 4;
  const int lc  = lane & 15;
  float gate = 0.f;
  if (EPI == 1) gate = gates[(m0 >> 10) * 8 + (n0 >> 10)];

#pragma unroll
  for (int mi = 0; mi < 8; ++mi) {
    const int rowb = m0 + (mi >> 2) * 128 + wm * 64 + (mi & 3) * 16 + lr4;
#pragma unroll
    for (int nj = 0; nj < 4; ++nj) {
      const int col = n0 + (nj >> 1) * 128 + wn * 32 + (nj & 1) * 16 + lc;
#pragma unroll
      for (int r = 0; r < 4; ++r) {
        const int row = rowb + r;
        float v = acc[mi][nj][r];
        if (EPI == 0) {
          v += bias[col];
          const int which = col >> 10;
          ((unsigned short*)out0)[(long long)which * 4194304 + (long long)row * 1024 + (col & 1023)] = f2bu(v);
        } else if (EPI == 1) {
          v += bias[col];
          float u = 0.7978845608028654f * (v + 0.044715f * v * v * v);
          u = fminf(fmaxf(u, -15.f), 15.f);
          float e2 = __expf(2.f * u);
          float th = (e2 - 1.f) / (e2 + 1.f);
          ((unsigned short*)out0)[(long long)row * 8192 + col] = f2bu(gate * 0.5f * v * (1.f + th));
        } else {
          if (z == 0) ((float*)out0)[(long long)row * 1024 + col] = v;
          else pbs[(long long)(z - 1) * 4194304 + (long long)row * 1024 + col] = f2bu(v);
        }
      }
    }
  }
}

// ---------------------------------------------------------------------------
// out = out + pb0 + pb1 + pb2 (bf16 partials) + bias2[b][n]
// ---------------------------------------------------------------------------
__global__ __launch_bounds__(256)
void reduce3(float* __restrict__ out, const unsigned short* __restrict__ pb,
             const float* __restrict__ bias2)
{
  const int i = (blockIdx.x * 256 + threadIdx.x) * 4;
  const int b = i >> 20;
  const int n = i & 1023;
  float4 a = *(const float4*)(out + i);
  ushort4 p0 = *(const ushort4*)(pb + i);
  ushort4 p1 = *(const ushort4*)(pb + 4194304 + i);
  ushort4 p2 = *(const ushort4*)(pb + 8388608 + i);
  float4 bb = *(const float4*)(bias2 + b * 1024 + n);
  a.x += b2f(p0.x) + b2f(p1.x) + b2f(p2.x) + bb.x;
  a.y += b2f(p0.y) + b2f(p1.y) + b2f(p2.y) + bb.y;
  a.z += b2f(p0.z) + b2f(p1.z) + b2f(p2.z) + bb.z;
  a.w += b2f(p0.w) + b2f(p1.w) + b2f(p2.w) + bb.w;
  *(float4*)(out + i) = a;
}

// ---------------------------------------------------------------------------
// Per-token cross-head attention (unchanged)
// ---------------------------------------------------------------------------
__global__ __launch_bounds__(256)
void attn_kernel(const unsigned short* __restrict__ Qb,
                 const unsigned short* __restrict__ Kb,
                 const unsigned short* __restrict__ Vb,
                 unsigned short* __restrict__ a)
{
  const int token = blockIdx.x;
  const int b = token >> 10, s = token & 1023;
  __shared__ float Qs[16][65], Ks[16][65], Vs[16][65];
  __shared__ float attn_s[16][17];
  const int t = threadIdx.x;
  const long long base = (long long)token * 1024;

  {
    const int i0 = t * 4;
    const int hh = i0 >> 6, dd = i0 & 63;
    ushort4 qv = *(const ushort4*)(Qb + base + i0);
    ushort4 kv = *(const ushort4*)(Kb + base + i0);
    ushort4 vv = *(const ushort4*)(Vb + base + i0);
    Qs[hh][dd+0]=b2f(qv.x); Qs[hh][dd+1]=b2f(qv.y); Qs[hh][dd+2]=b2f(qv.z); Qs[hh][dd+3]=b2f(qv.w);
    Ks[hh][dd+0]=b2f(kv.x); Ks[hh][dd+1]=b2f(kv.y); Ks[hh][dd+2]=b2f(kv.z); Ks[hh][dd+3]=b2f(kv.w);
    Vs[hh][dd+0]=b2f(vv.x); Vs[hh][dd+1]=b2f(vv.y); Vs[hh][dd+2]=b2f(vv.z); Vs[hh][dd+3]=b2f(vv.w);
  }
  __syncthreads();

  const int q = t >> 4, k = t & 15;
  float sc = 0.f;
#pragma unroll
  for (int d = 0; d < 64; ++d) sc += Qs[q][d] * Ks[k][d];
  sc *= 0.125f;
  float mx = sc;
#pragma unroll
  for (int m = 1; m < 16; m <<= 1) mx = fmaxf(mx, __shfl_xor(mx, m, 64));
  float ex = __expf(sc - mx);
  float sum = ex;
#pragma unroll
  for (int m = 1; m < 16; m <<= 1) sum += __shfl_xor(sum, m, 64);
  attn_s[q][k] = ex / sum;
  __syncthreads();

  const int hd = t & 63;
  const int wv = t >> 6;
#pragma unroll
  for (int r = 0; r < 4; ++r) {
    const int qq = wv * 4 + r;
    float o = 0.f;
#pragma unroll
    for (int kk = 0; kk < 16; ++kk) o += attn_s[qq][kk] * Vs[kk][hd];
    a[(long long)b * 1048576 + (long long)(qq * 64 + (s >> 4)) * 1024 + (s & 15) * 64 + hd] = f2bu(o);
  }
}

// ---------------------------------------------------------------------------
// Gating helpers (unchanged)
// ---------------------------------------------------------------------------
__global__ __launch_bounds__(256)
void col_sum_part(const unsigned short* __restrict__ a, float* __restrict__ part)
{
  const int bx = blockIdx.x;
  const int b = bx >> 2;
  const int d = (bx & 3) * 256 + threadIdx.x;
  const int y = blockIdx.y;
  const unsigned short* p = a + (long long)b * 1048576 + (long long)y * 131072 + d;
  float s = 0.f;
  for (int i = 0; i < 128; ++i) s += b2f(p[i * 1024]);
  part[(y * 4 + b) * 1024 + d] = s;
}

__global__ __launch_bounds__(256)
void gates_bias2(const float* __restrict__ part,
                 const float* __restrict__ Wg,
                 const float* __restrict__ bg,
                 const float* __restrict__ b2,
                 float* __restrict__ gates,
                 float* __restrict__ bias2)
{
  __shared__ float am[4][1024];
  __shared__ float sg[4][8];
  const int t = threadIdx.x;

  for (int i = t; i < 4096; i += 256) {
    const int b = i >> 10, d = i & 1023;
    float s = 0.f;
#pragma unroll
    for (int y = 0; y < 8; ++y) s += part[(y * 4 + b) * 1024 + d];
    am[b][d] = s * (1.f / 1024.f);
  }
  __syncthreads();

  const int pair = t >> 3, subl = t & 7;
  const int b = pair >> 3, e = pair & 7;
  float s = 0.f;
  for (int d = subl * 128; d < subl * 128 + 128; ++d) s += am[b][d] * Wg[d * 8 + e];
#pragma unroll
  for (int m = 1; m < 8; m <<= 1) s += __shfl_xor(s, m, 64);
  if (subl == 0) sg[b][e] = s + bg[e];
  __syncthreads();

  if (t < 4) {
    float mx = -1e30f;
    for (int ee = 0; ee < 8; ++ee) mx = fmaxf(mx, sg[t][ee]);
    float g[8]; float ssum = 0.f;
    for (int ee = 0; ee < 8; ++ee) { g[ee] = __expf(sg[t][ee] - mx); ssum += g[ee]; }
    for (int ee = 0; ee < 8; ++ee) { sg[t][ee] = g[ee] / ssum; gates[t * 8 + ee] = sg[t][ee]; }
  }
  __syncthreads();

  for (int i = t; i < 4096; i += 256) {
    const int bb = i >> 10, n = i & 1023;
    float ss = 0.f;
#pragma unroll
    for (int ee = 0; ee < 8; ++ee) ss += sg[bb][ee] * b2[ee * 1024 + n];
    bias2[i] = ss;
  }
}

// ---------------------------------------------------------------------------
// Host launch
// ---------------------------------------------------------------------------
extern "C" void kernel_launch(void* const* d_in, const int* in_sizes, int n_in,
                              void* d_out, int out_size, void* d_ws, size_t ws_size,
                              hipStream_t stream) {
  const float* x  = (const float*)d_in[0];
  const float* Wq = (const float*)d_in[1];
  const float* bq = (const float*)d_in[2];
  const float* Wk = (const float*)d_in[3];
  const float* bk = (const float*)d_in[4];
  const float* Wv = (const float*)d_in[5];
  const float* bv = (const float*)d_in[6];
  const float* Wg = (const float*)d_in[7];
  const float* bg = (const float*)d_in[8];
  const float* W1 = (const float*)d_in[9];
  const float* b1 = (const float*)d_in[10];
  const float* W2 = (const float*)d_in[11];
  const float* b2 = (const float*)d_in[12];
  float* out = (float*)d_out;

  if (ws_size < (size_t)109300000) return;

  char* ws = (char*)d_ws;
  unsigned short* xb   = (unsigned short*)(ws + 0);
  unsigned short* Wqt  = (unsigned short*)(ws + 8388608);     // [3072][1024]
  unsigned short* Qb   = (unsigned short*)(ws + 14680064);    // Q,K,V [3][4096][1024]
  unsigned short* hs   = (unsigned short*)(ws + 0);           // [4096][8192]
  unsigned short* abuf = (unsigned short*)(ws + 67108864);    // [4096][1024]
  unsigned short* pbs  = (unsigned short*)(ws + 67108864);    // 3x[4096][1024] bf16 (after EPI1)
  unsigned short* W1t  = (unsigned short*)(ws + 75497472);    // [8192][1024]
  unsigned short* W2t  = (unsigned short*)(ws + 92274688);    // [1024][8192]
  float* part  = (float*)(ws + 109051904);
  float* gates = (float*)(ws + 109051904 + 131072);
  float* bias2 = (float*)(ws + 109051904 + 131072 + 512);
  float* bqkv  = (float*)(ws + 109051904 + 131072 + 512 + 16384);

  dim3 tb(256);

  transpose_cvt<<<dim3(32,32,1), tb, 0, stream>>>(Wq, 0LL, Wqt,           0LL, 1024, 1024, 1024);
  transpose_cvt<<<dim3(32,32,1), tb, 0, stream>>>(Wk, 0LL, Wqt + 1048576, 0LL, 1024, 1024, 1024);
  transpose_cvt<<<dim3(32,32,1), tb, 0, stream>>>(Wv, 0LL, Wqt + 2097152, 0LL, 1024, 1024, 1024);
  transpose_cvt<<<dim3(32,32,8), tb, 0, stream>>>(W1, 1048576LL, W1t, 1048576LL, 1024, 1024, 1024);
  transpose_cvt<<<dim3(32,32,8), tb, 0, stream>>>(W2, 1048576LL, W2t, 1024LL,    8192, 1024, 1024);
  cvt_f32_bf16<<<4096, tb, 0, stream>>>(x, xb, 4194304);
  hipMemcpyAsync(bqkv,        bq, 4096, hipMemcpyDeviceToDevice, stream);
  hipMemcpyAsync(bqkv + 1024, bk, 4096, hipMemcpyDeviceToDevice, stream);
  hipMemcpyAsync(bqkv + 2048, bv, 4096, hipMemcpyDeviceToDevice, stream);

  // QKV: M=4096, N=3072 (flat), K=1024
  gemm256<0><<<dim3(12,16,1), 512, 0, stream>>>(xb, 1024, Wqt, 1024, bqkv,
                                                Qb, nullptr, 1024, nullptr);
  // Attention -> scrambled a
  attn_kernel<<<4096, tb, 0, stream>>>(Qb, Qb + 4194304, Qb + 8388608, abuf);
  // Gating
  col_sum_part<<<dim3(16,8), tb, 0, stream>>>(abuf, part);
  gates_bias2<<<1, tb, 0, stream>>>(part, Wg, bg, b2, gates, bias2);
  // Expert up-proj + gelu + gate: M=4096, N=8192 (flat experts), K=1024
  gemm256<1><<<dim3(32,16,1), 512, 0, stream>>>(abuf, 1024, W1t, 1024, b1,
                                                hs, nullptr, 1024, gates);
  // Final down-proj: M=4096, N=1024, K=8192, split-K 4 (z=0 -> out f32, z>0 -> bf16 partials)
  gemm256<3><<<dim3(4,16,4), 512, 0, stream>>>(hs, 8192, W2t, 8192, nullptr,
                                               out, pbs, 2048, nullptr);
  reduce3<<<4096, tb, 0, stream>>>(out, pbs, bias2);
}

// Round 5
// 269.277 us; speedup vs baseline: 1.5555x; 1.0549x over previous
//
#include <hip/hip_runtime.h>
#include <stdint.h>

#define AS1 __attribute__((address_space(1)))
#define AS3 __attribute__((address_space(3)))

typedef short v8s __attribute__((ext_vector_type(8)));
typedef float v4f __attribute__((ext_vector_type(4)));

__device__ __forceinline__ float b2f(unsigned short u) {
  return __uint_as_float(((unsigned int)u) << 16);
}
__device__ __forceinline__ unsigned short f2bu(float f) {
  unsigned int u = __float_as_uint(f);
  u += 0x7fffu + ((u >> 16) & 1u);
  return (unsigned short)(u >> 16);
}

__device__ __forceinline__ void gload16(const void* g, const void* l) {
  __builtin_amdgcn_global_load_lds(
      (const AS1 void*)(uintptr_t)g,
      (AS3 void*)(unsigned)(uintptr_t)l,
      16, 0, 0);
}

#define SB0 __builtin_amdgcn_sched_barrier(0)
#define BAR do { SB0; __builtin_amdgcn_s_barrier(); SB0; } while (0)
#define VMC4 asm volatile("s_waitcnt vmcnt(4)" ::: "memory")
#define VMC0 asm volatile("s_waitcnt vmcnt(0)" ::: "memory")

// ---------------------------------------------------------------------------
// Transpose + f32->bf16 convert: src [K][N] f32 (ld=N) -> dst [N][K] bf16
// ---------------------------------------------------------------------------
__global__ __launch_bounds__(256)
void transpose_cvt(const float* __restrict__ src, long long srcZ,
                   unsigned short* __restrict__ dst, long long dstZ, int ld_dst,
                   int K, int N)
{
  __shared__ float t[32][33];
  const int e = blockIdx.z;
  src += (long long)e * srcZ;
  dst += (long long)e * dstZ;
  const int k0 = blockIdx.y * 32, n0 = blockIdx.x * 32;
  const int tx = threadIdx.x & 31, ty = threadIdx.x >> 5;
#pragma unroll
  for (int r = 0; r < 32; r += 8)
    t[ty + r][tx] = src[(long long)(k0 + ty + r) * N + n0 + tx];
  __syncthreads();
#pragma unroll
  for (int r = 0; r < 32; r += 8) {
    const int n = ty + r;
    dst[(long long)(n0 + n) * ld_dst + k0 + tx] = f2bu(t[tx][n]);
  }
}

__global__ __launch_bounds__(256)
void cvt_f32_bf16(const float* __restrict__ src, unsigned short* __restrict__ dst, int n)
{
  const int i = (blockIdx.x * 256 + threadIdx.x) * 4;
  if (i >= n) return;
  float4 v = *(const float4*)(src + i);
  ushort4 o;
  o.x = f2bu(v.x); o.y = f2bu(v.y); o.z = f2bu(v.z); o.w = f2bu(v.w);
  *(ushort4*)(dst + i) = o;
}

// ---------------------------------------------------------------------------
// 256x256 8-phase bf16 GEMM (T2 st_16x32 + T3 + T4 + T5), BK=64, 8 waves.
// LDS half-tile layout: SUBTILED [row/16][col/32][16][32] elems, 1024B each,
// with st_16x32 swizzle: byte ^= ((byte>>9)&1)<<5  (within each subtile).
// Snake quadrant order (0,1)->(0,0)->(1,0)->(1,1): each phase re-reads exactly
// ONE operand set (28 ds_read_b128/buf vs 48 naive), no extra registers.
// EPI 0: bf16 Q/K/V out = acc + bias[col]; out slab = col>>10
// EPI 1: bf16 out = gate * gelu_new(acc + bias[col])  (hs, ld 8192)
// EPI 3: split-K partial: z=0 -> f32 out0, z>0 -> bf16 pbs[z-1]
// ---------------------------------------------------------------------------
template<int MH>
__device__ __forceinline__ void read_a(v8s af[4][2],
    const unsigned short* pa, int wm, int rswz)
{
#pragma unroll
  for (int i = 0; i < 4; ++i)
#pragma unroll
    for (int s = 0; s < 2; ++s)
      af[i][s] = *(const v8s*)(pa + MH*8192 + ((((wm*4 + i)*2 + s) << 9) | rswz));
}

template<int NH>
__device__ __forceinline__ void read_b(v8s bfr[2][2],
    const unsigned short* pb, int wn, int rswz)
{
#pragma unroll
  for (int j = 0; j < 2; ++j)
#pragma unroll
    for (int s = 0; s < 2; ++s)
      bfr[j][s] = *(const v8s*)(pb + NH*8192 + ((((wn*2 + j)*2 + s) << 9) | rswz));
}

template<int MH, int NH>
__device__ __forceinline__ void quad_mfma(v4f acc[8][4], v8s af[4][2], v8s bfr[2][2])
{
  __builtin_amdgcn_s_setprio(1);
#pragma unroll
  for (int i = 0; i < 4; ++i)
#pragma unroll
    for (int j = 0; j < 2; ++j)
#pragma unroll
      for (int s = 0; s < 2; ++s)
        acc[MH*4+i][NH*2+j] = __builtin_amdgcn_mfma_f32_16x16x32_bf16(
            af[i][s], bfr[j][s], acc[MH*4+i][NH*2+j], 0, 0, 0);
  __builtin_amdgcn_s_setprio(0);
}

// stage one 128-row half-tile (2 x gload16 per thread, 1 subtile each)
#define STAGE(G, LD, LDSBASE, GROW0, KT) do { \
    gload16((G) + (long long)((GROW0) + sRow) * (LD) + (KT) + sCol, \
            (LDSBASE) + w*512); \
    gload16((G) + (long long)((GROW0) + 64 + sRow) * (LD) + (KT) + sCol, \
            (LDSBASE) + 4096 + w*512); \
  } while (0)

template<int EPI>
__global__ __launch_bounds__(512, 2)
void gemm256(const unsigned short* __restrict__ A, int lda,
             const unsigned short* __restrict__ Bt, int ldb,
             const float* __restrict__ bias,
             void* __restrict__ out0, unsigned short* __restrict__ pbs,
             int kLen, const float* __restrict__ gates)
{
  __shared__ __align__(16) unsigned short lds[65536];   // 128 KiB
  unsigned short* As0 = lds;
  unsigned short* As1 = lds + 16384;
  unsigned short* Bs0 = lds + 32768;
  unsigned short* Bs1 = lds + 49152;

  const int tid  = threadIdx.x;
  const int lane = tid & 63;
  const int w    = tid >> 6;        // 0..7
  const int wm   = w >> 2;          // 0..1
  const int wn   = w & 3;           // 0..3
  const int m0   = blockIdx.y * 256;
  const int n0   = blockIdx.x * 256;
  const int z    = blockIdx.z;
  const int kBase = (EPI == 3) ? z * kLen : 0;

  // staging (subtile w at g=0, subtile 8+w at g=1): lane l fills 16B at l*16
  // source row/col inverse-swizzled (st_16x32: byte^=((byte>>9)&1)<<5)
  const int sRow = (w >> 1) * 16 + (lane >> 2);
  const int sCol = (w & 1) * 32 + (((lane & 3) * 8) ^ (((lane >> 5) & 1) << 4));
  // read: row-in-subtile rr, k-group kgrp; swizzled within-subtile elem offset
  const int rr   = lane & 15;
  const int kgrp = lane >> 4;
  const int rswz = (rr * 32 + kgrp * 8) ^ ((rr & 8) << 1);

  v4f acc[8][4] = {};
  v8s af[4][2], bfr[2][2];

  const int iters = kLen >> 7;   // 2 K-tiles (BK=64) per iteration

  // ---- prologue: buf0 <- tile0 (all), buf1 <- tile1 (A-lo, B-lo) ----
  STAGE(A,  lda, As0,        m0,       kBase);
  STAGE(A,  lda, As0 + 8192, m0 + 128, kBase);
  STAGE(Bt, ldb, Bs0,        n0,       kBase);
  STAGE(Bt, ldb, Bs0 + 8192, n0 + 128, kBase);
  STAGE(A,  lda, As1,        m0,       kBase + 64);
  STAGE(Bt, ldb, Bs1,        n0,       kBase + 64);
  VMC4;   // tile0 landed; tile1 A-lo/B-lo (4 loads) in flight
  BAR;

  for (int it = 0; it < iters; ++it) {
    const bool nl = (it != iters - 1);
    const int kT1 = kBase + (2*it + 1) * 64;
    const int kT2 = kT1 + 64;
    const int kT3 = kT1 + 128;

    // ---------- buf0 (tile 2it), snake (0,1),(0,0),(1,0),(1,1) ----------
    // ph1: read A-lo + B-hi | stage buf1.A-hi(T1)
    read_a<0>(af, As0, wm, rswz);
    read_b<1>(bfr, Bs0, wn, rswz);
    STAGE(A, lda, As1 + 8192, m0 + 128, kT1);
    BAR; quad_mfma<0,1>(acc, af, bfr); BAR;
    // ph2: read B-lo (af held) | stage buf1.B-hi(T1)
    read_b<0>(bfr, Bs0, wn, rswz);
    STAGE(Bt, ldb, Bs1 + 8192, n0 + 128, kT1);
    BAR; quad_mfma<0,0>(acc, af, bfr); BAR;
    // ph3: read A-hi (bfr held) | stage buf0.A-lo(T+2)
    read_a<1>(af, As0, wm, rswz);
    if (nl) STAGE(A, lda, As0, m0, kT2);
    BAR; quad_mfma<1,0>(acc, af, bfr); BAR;
    // ph4: re-read B-hi (af held) | stage buf0.B-lo(T+2) | vmcnt
    read_b<1>(bfr, Bs0, wn, rswz);
    if (nl) STAGE(Bt, ldb, Bs0, n0, kT2);
    BAR; quad_mfma<1,1>(acc, af, bfr);
    if (nl) { VMC4; } else { VMC0; }
    BAR;
    // ---------- buf1 (tile 2it+1), same snake ----------
    // ph5: read A-lo + B-hi | stage buf0.A-hi(T+2)
    read_a<0>(af, As1, wm, rswz);
    read_b<1>(bfr, Bs1, wn, rswz);
    if (nl) STAGE(A, lda, As0 + 8192, m0 + 128, kT2);
    BAR; quad_mfma<0,1>(acc, af, bfr); BAR;
    // ph6: read B-lo | stage buf0.B-hi(T+2)
    read_b<0>(bfr, Bs1, wn, rswz);
    if (nl) STAGE(Bt, ldb, Bs0 + 8192, n0 + 128, kT2);
    BAR; quad_mfma<0,0>(acc, af, bfr); BAR;
    // ph7: read A-hi | stage buf1.A-lo(T+3)
    read_a<1>(af, As1, wm, rswz);
    if (nl) STAGE(A, lda, As1, m0, kT3);
    BAR; quad_mfma<1,0>(acc, af, bfr); BAR;
    // ph8: re-read B-hi | stage buf1.B-lo(T+3) | vmcnt
    read_b<1>(bfr, Bs1, wn, rswz);
    if (nl) STAGE(Bt, ldb, Bs1, n0, kT3);
    BAR; quad_mfma<1,1>(acc, af, bfr);
    if (nl) { VMC4; } else { VMC0; }
    BAR;
  }

  // ---- epilogue ----
  const int lr4 = (lane >> 4) * 4;
  const int lc  = lane & 15;
  float gate = 0.f;
  if (EPI == 1) gate = gates[(m0 >> 10) * 8 + (n0 >> 10)];

#pragma unroll
  for (int mi = 0; mi < 8; ++mi) {
    const int rowb = m0 + (mi >> 2) * 128 + wm * 64 + (mi & 3) * 16 + lr4;
#pragma unroll
    for (int nj = 0; nj < 4; ++nj) {
      const int col = n0 + (nj >> 1) * 128 + wn * 32 + (nj & 1) * 16 + lc;
#pragma unroll
      for (int r = 0; r < 4; ++r) {
        const int row = rowb + r;
        float v = acc[mi][nj][r];
        if (EPI == 0) {
          v += bias[col];
          const int which = col >> 10;
          ((unsigned short*)out0)[(long long)which * 4194304 + (long long)row * 1024 + (col & 1023)] = f2bu(v);
        } else if (EPI == 1) {
          v += bias[col];
          float u = 0.7978845608028654f * (v + 0.044715f * v * v * v);
          u = fminf(fmaxf(u, -15.f), 15.f);
          float e2 = __expf(2.f * u);
          float th = (e2 - 1.f) / (e2 + 1.f);
          ((unsigned short*)out0)[(long long)row * 8192 + col] = f2bu(gate * 0.5f * v * (1.f + th));
        } else {
          if (z == 0) ((float*)out0)[(long long)row * 1024 + col] = v;
          else pbs[(long long)(z - 1) * 4194304 + (long long)row * 1024 + col] = f2bu(v);
        }
      }
    }
  }
}

// ---------------------------------------------------------------------------
// out = out + pb0 + pb1 + pb2 (bf16 partials) + bias2[b][n]
// ---------------------------------------------------------------------------
__global__ __launch_bounds__(256)
void reduce3(float* __restrict__ out, const unsigned short* __restrict__ pb,
             const float* __restrict__ bias2)
{
  const int i = (blockIdx.x * 256 + threadIdx.x) * 4;
  const int b = i >> 20;
  const int n = i & 1023;
  float4 a = *(const float4*)(out + i);
  ushort4 p0 = *(const ushort4*)(pb + i);
  ushort4 p1 = *(const ushort4*)(pb + 4194304 + i);
  ushort4 p2 = *(const ushort4*)(pb + 8388608 + i);
  float4 bb = *(const float4*)(bias2 + b * 1024 + n);
  a.x += b2f(p0.x) + b2f(p1.x) + b2f(p2.x) + bb.x;
  a.y += b2f(p0.y) + b2f(p1.y) + b2f(p2.y) + bb.y;
  a.z += b2f(p0.z) + b2f(p1.z) + b2f(p2.z) + bb.z;
  a.w += b2f(p0.w) + b2f(p1.w) + b2f(p2.w) + bb.w;
  *(float4*)(out + i) = a;
}

// ---------------------------------------------------------------------------
// Per-token cross-head attention (unchanged)
// ---------------------------------------------------------------------------
__global__ __launch_bounds__(256)
void attn_kernel(const unsigned short* __restrict__ Qb,
                 const unsigned short* __restrict__ Kb,
                 const unsigned short* __restrict__ Vb,
                 unsigned short* __restrict__ a)
{
  const int token = blockIdx.x;
  const int b = token >> 10, s = token & 1023;
  __shared__ float Qs[16][65], Ks[16][65], Vs[16][65];
  __shared__ float attn_s[16][17];
  const int t = threadIdx.x;
  const long long base = (long long)token * 1024;

  {
    const int i0 = t * 4;
    const int hh = i0 >> 6, dd = i0 & 63;
    ushort4 qv = *(const ushort4*)(Qb + base + i0);
    ushort4 kv = *(const ushort4*)(Kb + base + i0);
    ushort4 vv = *(const ushort4*)(Vb + base + i0);
    Qs[hh][dd+0]=b2f(qv.x); Qs[hh][dd+1]=b2f(qv.y); Qs[hh][dd+2]=b2f(qv.z); Qs[hh][dd+3]=b2f(qv.w);
    Ks[hh][dd+0]=b2f(kv.x); Ks[hh][dd+1]=b2f(kv.y); Ks[hh][dd+2]=b2f(kv.z); Ks[hh][dd+3]=b2f(kv.w);
    Vs[hh][dd+0]=b2f(vv.x); Vs[hh][dd+1]=b2f(vv.y); Vs[hh][dd+2]=b2f(vv.z); Vs[hh][dd+3]=b2f(vv.w);
  }
  __syncthreads();

  const int q = t >> 4, k = t & 15;
  float sc = 0.f;
#pragma unroll
  for (int d = 0; d < 64; ++d) sc += Qs[q][d] * Ks[k][d];
  sc *= 0.125f;
  float mx = sc;
#pragma unroll
  for (int m = 1; m < 16; m <<= 1) mx = fmaxf(mx, __shfl_xor(mx, m, 64));
  float ex = __expf(sc - mx);
  float sum = ex;
#pragma unroll
  for (int m = 1; m < 16; m <<= 1) sum += __shfl_xor(sum, m, 64);
  attn_s[q][k] = ex / sum;
  __syncthreads();

  const int hd = t & 63;
  const int wv = t >> 6;
#pragma unroll
  for (int r = 0; r < 4; ++r) {
    const int qq = wv * 4 + r;
    float o = 0.f;
#pragma unroll
    for (int kk = 0; kk < 16; ++kk) o += attn_s[qq][kk] * Vs[kk][hd];
    a[(long long)b * 1048576 + (long long)(qq * 64 + (s >> 4)) * 1024 + (s & 15) * 64 + hd] = f2bu(o);
  }
}

// ---------------------------------------------------------------------------
// Gating helpers (unchanged)
// ---------------------------------------------------------------------------
__global__ __launch_bounds__(256)
void col_sum_part(const unsigned short* __restrict__ a, float* __restrict__ part)
{
  const int bx = blockIdx.x;
  const int b = bx >> 2;
  const int d = (bx & 3) * 256 + threadIdx.x;
  const int y = blockIdx.y;
  const unsigned short* p = a + (long long)b * 1048576 + (long long)y * 131072 + d;
  float s = 0.f;
  for (int i = 0; i < 128; ++i) s += b2f(p[i * 1024]);
  part[(y * 4 + b) * 1024 + d] = s;
}

__global__ __launch_bounds__(256)
void gates_bias2(const float* __restrict__ part,
                 const float* __restrict__ Wg,
                 const float* __restrict__ bg,
                 const float* __restrict__ b2,
                 float* __restrict__ gates,
                 float* __restrict__ bias2)
{
  __shared__ float am[4][1024];
  __shared__ float sg[4][8];
  const int t = threadIdx.x;

  for (int i = t; i < 4096; i += 256) {
    const int b = i >> 10, d = i & 1023;
    float s = 0.f;
#pragma unroll
    for (int y = 0; y < 8; ++y) s += part[(y * 4 + b) * 1024 + d];
    am[b][d] = s * (1.f / 1024.f);
  }
  __syncthreads();

  const int pair = t >> 3, subl = t & 7;
  const int b = pair >> 3, e = pair & 7;
  float s = 0.f;
  for (int d = subl * 128; d < subl * 128 + 128; ++d) s += am[b][d] * Wg[d * 8 + e];
#pragma unroll
  for (int m = 1; m < 8; m <<= 1) s += __shfl_xor(s, m, 64);
  if (subl == 0) sg[b][e] = s + bg[e];
  __syncthreads();

  if (t < 4) {
    float mx = -1e30f;
    for (int ee = 0; ee < 8; ++ee) mx = fmaxf(mx, sg[t][ee]);
    float g[8]; float ssum = 0.f;
    for (int ee = 0; ee < 8; ++ee) { g[ee] = __expf(sg[t][ee] - mx); ssum += g[ee]; }
    for (int ee = 0; ee < 8; ++ee) { sg[t][ee] = g[ee] / ssum; gates[t * 8 + ee] = sg[t][ee]; }
  }
  __syncthreads();

  for (int i = t; i < 4096; i += 256) {
    const int bb = i >> 10, n = i & 1023;
    float ss = 0.f;
#pragma unroll
    for (int ee = 0; ee < 8; ++ee) ss += sg[bb][ee] * b2[ee * 1024 + n];
    bias2[i] = ss;
  }
}

// ---------------------------------------------------------------------------
// Host launch
// ---------------------------------------------------------------------------
extern "C" void kernel_launch(void* const* d_in, const int* in_sizes, int n_in,
                              void* d_out, int out_size, void* d_ws, size_t ws_size,
                              hipStream_t stream) {
  const float* x  = (const float*)d_in[0];
  const float* Wq = (const float*)d_in[1];
  const float* bq = (const float*)d_in[2];
  const float* Wk = (const float*)d_in[3];
  const float* bk = (const float*)d_in[4];
  const float* Wv = (const float*)d_in[5];
  const float* bv = (const float*)d_in[6];
  const float* Wg = (const float*)d_in[7];
  const float* bg = (const float*)d_in[8];
  const float* W1 = (const float*)d_in[9];
  const float* b1 = (const float*)d_in[10];
  const float* W2 = (const float*)d_in[11];
  const float* b2 = (const float*)d_in[12];
  float* out = (float*)d_out;

  if (ws_size < (size_t)109300000) return;

  char* ws = (char*)d_ws;
  unsigned short* xb   = (unsigned short*)(ws + 0);
  unsigned short* Wqt  = (unsigned short*)(ws + 8388608);     // [3072][1024]
  unsigned short* Qb   = (unsigned short*)(ws + 14680064);    // Q,K,V [3][4096][1024]
  unsigned short* hs   = (unsigned short*)(ws + 0);           // [4096][8192]
  unsigned short* abuf = (unsigned short*)(ws + 67108864);    // [4096][1024]
  unsigned short* pbs  = (unsigned short*)(ws + 67108864);    // 3x[4096][1024] bf16 (after EPI1)
  unsigned short* W1t  = (unsigned short*)(ws + 75497472);    // [8192][1024]
  unsigned short* W2t  = (unsigned short*)(ws + 92274688);    // [1024][8192]
  float* part  = (float*)(ws + 109051904);
  float* gates = (float*)(ws + 109051904 + 131072);
  float* bias2 = (float*)(ws + 109051904 + 131072 + 512);
  float* bqkv  = (float*)(ws + 109051904 + 131072 + 512 + 16384);

  dim3 tb(256);

  transpose_cvt<<<dim3(32,32,1), tb, 0, stream>>>(Wq, 0LL, Wqt,           0LL, 1024, 1024, 1024);
  transpose_cvt<<<dim3(32,32,1), tb, 0, stream>>>(Wk, 0LL, Wqt + 1048576, 0LL, 1024, 1024, 1024);
  transpose_cvt<<<dim3(32,32,1), tb, 0, stream>>>(Wv, 0LL, Wqt + 2097152, 0LL, 1024, 1024, 1024);
  transpose_cvt<<<dim3(32,32,8), tb, 0, stream>>>(W1, 1048576LL, W1t, 1048576LL, 1024, 1024, 1024);
  transpose_cvt<<<dim3(32,32,8), tb, 0, stream>>>(W2, 1048576LL, W2t, 1024LL,    8192, 1024, 1024);
  cvt_f32_bf16<<<4096, tb, 0, stream>>>(x, xb, 4194304);
  hipMemcpyAsync(bqkv,        bq, 4096, hipMemcpyDeviceToDevice, stream);
  hipMemcpyAsync(bqkv + 1024, bk, 4096, hipMemcpyDeviceToDevice, stream);
  hipMemcpyAsync(bqkv + 2048, bv, 4096, hipMemcpyDeviceToDevice, stream);

  // QKV: M=4096, N=3072 (flat), K=1024
  gemm256<0><<<dim3(12,16,1), 512, 0, stream>>>(xb, 1024, Wqt, 1024, bqkv,
                                                Qb, nullptr, 1024, nullptr);
  // Attention -> scrambled a
  attn_kernel<<<4096, tb, 0, stream>>>(Qb, Qb + 4194304, Qb + 8388608, abuf);
  // Gating
  col_sum_part<<<dim3(16,8), tb, 0, stream>>>(abuf, part);
  gates_bias2<<<1, tb, 0, stream>>>(part, Wg, bg, b2, gates, bias2);
  // Expert up-proj + gelu + gate: M=4096, N=8192 (flat experts), K=1024
  gemm256<1><<<dim3(32,16,1), 512, 0, stream>>>(abuf, 1024, W1t, 1024, b1,
                                                hs, nullptr, 1024, gates);
  // Final down-proj: M=4096, N=1024, K=8192, split-K 4 (z=0 -> out f32, z>0 -> bf16 partials)
  gemm256<3><<<dim3(4,16,4), 512, 0, stream>>>(hs, 8192, W2t, 8192, nullptr,
                                               out, pbs, 2048, nullptr);
  reduce3<<<4096, tb, 0, stream>>>(out, pbs, bias2);
}